// Round 1
// baseline (1276.627 us; speedup 1.0000x reference)
//
#include <hip/hip_runtime.h>

#define NA_N 50000
#define NB_N 50000
#define NE   1000000
#define DF   128
#define NG_N 64
#define NC_N 10

// ---------------- CSR build ----------------

__global__ void count_deg_k(const int* __restrict__ dst, int* __restrict__ deg, int n) {
    int i = blockIdx.x * 256 + threadIdx.x;
    if (i < n) atomicAdd(&deg[dst[i]], 1);
}

__global__ void scan_block_k(const int* __restrict__ deg, int n,
                             int* __restrict__ offs, int* __restrict__ bsums) {
    __shared__ int s[256];
    int t = threadIdx.x, i = blockIdx.x * 256 + t;
    int v = (i < n) ? deg[i] : 0;
    s[t] = v;
    __syncthreads();
    for (int d = 1; d < 256; d <<= 1) {
        int x = (t >= d) ? s[t - d] : 0;
        __syncthreads();
        if (t >= d) s[t] += x;
        __syncthreads();
    }
    if (i < n) offs[i] = s[t] - v;           // exclusive within block
    if (t == 255) bsums[blockIdx.x] = s[255]; // block total
}

__global__ void scan_sums_k(int* bsums, int nb) {
    __shared__ int s[256];
    int t = threadIdx.x;
    int v = (t < nb) ? bsums[t] : 0;
    s[t] = v;
    __syncthreads();
    for (int d = 1; d < 256; d <<= 1) {
        int x = (t >= d) ? s[t - d] : 0;
        __syncthreads();
        if (t >= d) s[t] += x;
        __syncthreads();
    }
    if (t < nb) bsums[t] = s[t] - v;          // exclusive
}

__global__ void add_base_k(int* __restrict__ offs, const int* __restrict__ bsums,
                           int n, int* __restrict__ cur, int total) {
    int i = blockIdx.x * 256 + threadIdx.x;
    if (i < n) {
        int v = offs[i] + bsums[i >> 8];
        offs[i] = v;
        cur[i] = v;
    }
    if (i == 0) offs[n] = total;
}

__global__ void fill_csr_k(const int* __restrict__ src, const int* __restrict__ dst,
                           int* __restrict__ cur, int* __restrict__ ss, int n) {
    int i = blockIdx.x * 256 + threadIdx.x;
    if (i < n) {
        int p = atomicAdd(&cur[dst[i]], 1);
        ss[p] = src[i];
    }
}

// ---------------- segment mean (gather side, 1 wave per dst node) ----------------

__global__ __launch_bounds__(256) void aggregate_k(
    const float* __restrict__ xs, const int* __restrict__ offs,
    const int* __restrict__ ss, float* __restrict__ mean, int ndst) {
    int node = (blockIdx.x * 256 + threadIdx.x) >> 6;
    int lane = threadIdx.x & 63;
    if (node >= ndst) return;
    int o0 = offs[node], o1 = offs[node + 1];
    const float2* x2 = (const float2*)xs;
    float ax = 0.f, ay = 0.f;
    int e = o0;
    for (; e + 1 < o1; e += 2) {
        int s0 = ss[e], s1 = ss[e + 1];
        float2 v0 = x2[s0 * 64 + lane];
        float2 v1 = x2[s1 * 64 + lane];
        ax += v0.x + v1.x;
        ay += v0.y + v1.y;
    }
    if (e < o1) {
        float2 v = x2[ss[e] * 64 + lane];
        ax += v.x;
        ay += v.y;
    }
    int cnt = o1 - o0;
    float inv = 1.0f / (float)(cnt > 0 ? cnt : 1);
    float2 r;
    r.x = ax * inv;
    r.y = ay * inv;
    ((float2*)mean)[node * 64 + lane] = r;
}

// ---------------- fused multi-matrix GEMM: out = relu(sum_m A_m @ W_m + b0 [+ b1]) ----------------
// A_m: [nrows,128], W_m: [128,128] row-major, out: [nrows,128]
// block: 256 threads (16x16), tile 64 rows x 128 cols, BK=16

__global__ __launch_bounds__(256) void gemm_fused_k(
    const float* __restrict__ A0, const float* __restrict__ W0,
    const float* __restrict__ A1, const float* __restrict__ W1,
    const float* __restrict__ A2, const float* __restrict__ W2,
    const float* __restrict__ b0, const float* __restrict__ b1,
    int nmats, int nrows, float* __restrict__ out) {
    __shared__ float As[64 * 20];   // stride 20 -> max 2-way bank aliasing (free)
    __shared__ float Ws[16 * 128];
    int tid = threadIdx.x;
    int tx = tid & 15, ty = tid >> 4;
    int row0 = blockIdx.x * 64;

    float acc[4][8];
#pragma unroll
    for (int i = 0; i < 4; i++)
#pragma unroll
        for (int j = 0; j < 8; j++) acc[i][j] = 0.f;

    for (int m = 0; m < nmats; m++) {
        const float* A = (m == 0) ? A0 : ((m == 1) ? A1 : A2);
        const float* W = (m == 0) ? W0 : ((m == 1) ? W1 : W2);
        for (int k0 = 0; k0 < DF; k0 += 16) {
            // load from global into registers first
            int r = tid >> 2, kk = (tid & 3) << 2;
            int row = row0 + r;
            if (row >= nrows) row = nrows - 1;
            float4 av = *(const float4*)(A + (size_t)row * DF + k0 + kk);
            int wk = tid >> 4, wc = (tid & 15) * 8;
            float4 wv0 = *(const float4*)(W + (k0 + wk) * DF + wc);
            float4 wv1 = *(const float4*)(W + (k0 + wk) * DF + wc + 4);
            __syncthreads();   // previous tile's reads done
            *(float4*)(As + r * 20 + kk) = av;
            *(float4*)(Ws + wk * 128 + wc) = wv0;
            *(float4*)(Ws + wk * 128 + wc + 4) = wv1;
            __syncthreads();
#pragma unroll
            for (int k = 0; k < 16; k++) {
                float a0 = As[(ty * 4 + 0) * 20 + k];
                float a1 = As[(ty * 4 + 1) * 20 + k];
                float a2 = As[(ty * 4 + 2) * 20 + k];
                float a3 = As[(ty * 4 + 3) * 20 + k];
                float4 w0 = *(const float4*)(Ws + k * 128 + tx * 8);
                float4 w1 = *(const float4*)(Ws + k * 128 + tx * 8 + 4);
                float wv[8] = {w0.x, w0.y, w0.z, w0.w, w1.x, w1.y, w1.z, w1.w};
                float av4[4] = {a0, a1, a2, a3};
#pragma unroll
                for (int i = 0; i < 4; i++)
#pragma unroll
                    for (int j = 0; j < 8; j++) acc[i][j] += av4[i] * wv[j];
            }
        }
    }

    float bj[8];
#pragma unroll
    for (int j = 0; j < 8; j++) {
        int c = tx * 8 + j;
        float bb = b0[c];
        if (b1) bb += b1[c];
        bj[j] = bb;
    }
#pragma unroll
    for (int i = 0; i < 4; i++) {
        int row = row0 + ty * 4 + i;
        if (row < nrows) {
            float4 o0, o1;
            o0.x = fmaxf(acc[i][0] + bj[0], 0.f);
            o0.y = fmaxf(acc[i][1] + bj[1], 0.f);
            o0.z = fmaxf(acc[i][2] + bj[2], 0.f);
            o0.w = fmaxf(acc[i][3] + bj[3], 0.f);
            o1.x = fmaxf(acc[i][4] + bj[4], 0.f);
            o1.y = fmaxf(acc[i][5] + bj[5], 0.f);
            o1.z = fmaxf(acc[i][6] + bj[6], 0.f);
            o1.w = fmaxf(acc[i][7] + bj[7], 0.f);
            *(float4*)(out + (size_t)row * DF + tx * 8) = o0;
            *(float4*)(out + (size_t)row * DF + tx * 8 + 4) = o1;
        }
    }
}

// ---------------- misc small kernels ----------------

__global__ void add_mats_k(const float* __restrict__ a, const float* __restrict__ b,
                           float* __restrict__ o, int n) {
    int i = blockIdx.x * 256 + threadIdx.x;
    if (i < n) o[i] = a[i] + b[i];
}

__device__ __forceinline__ int lb_search(const int* a, int n, int v) {
    int lo = 0, hi = n;
    while (lo < hi) {
        int m = (lo + hi) >> 1;
        if (a[m] < v) lo = m + 1; else hi = m;
    }
    return lo;
}

__global__ void pool_sum_k(const float* __restrict__ xa, const int* __restrict__ batch,
                           float* __restrict__ pooled) {
    __shared__ int slo, shi;
    int g = blockIdx.x, t = threadIdx.x;
    if (t == 0) {
        slo = lb_search(batch, NA_N, g);
        shi = lb_search(batch, NA_N, g + 1);
    }
    __syncthreads();
    int lo = slo, hi = shi;
    float s = 0.f;
    for (int r = lo; r < hi; r++) s += xa[(size_t)r * DF + t];
    int cnt = hi - lo;
    pooled[g * DF + t] = s / (float)(cnt > 0 ? cnt : 1);
}

__global__ void out_head_k(const float* __restrict__ pooled, const float* __restrict__ Wout,
                           const float* __restrict__ bout, float* __restrict__ out) {
    int tid = threadIdx.x;
    if (tid >= NG_N * NC_N) return;
    int g = tid / NC_N, c = tid % NC_N;
    float s = bout[c];
    for (int k = 0; k < DF; k++) s += pooled[g * DF + k] * Wout[k * NC_N + c];
    out[tid] = s;
}

// ---------------- launcher ----------------

extern "C" void kernel_launch(void* const* d_in, const int* in_sizes, int n_in,
                              void* d_out, int out_size, void* d_ws, size_t ws_size,
                              hipStream_t stream) {
    const float* x_a = (const float*)d_in[0];
    const float* x_b = (const float*)d_in[1];
    const int* ei_aa = (const int*)d_in[2];
    const int* ei_ab = (const int*)d_in[3];
    const int* ei_ba = (const int*)d_in[4];
    const int* batch = (const int*)d_in[5];
    const float *Wn0_aa = (const float*)d_in[6],  *bn0_aa = (const float*)d_in[7],  *Wr0_aa = (const float*)d_in[8];
    const float *Wn0_ab = (const float*)d_in[9],  *bn0_ab = (const float*)d_in[10], *Wr0_ab = (const float*)d_in[11];
    const float *Wn0_ba = (const float*)d_in[12], *bn0_ba = (const float*)d_in[13], *Wr0_ba = (const float*)d_in[14];
    const float *Wn1_aa = (const float*)d_in[15], *bn1_aa = (const float*)d_in[16], *Wr1_aa = (const float*)d_in[17];
    // d_in[18..20] = Wn1_ab, bn1_ab, Wr1_ab — unused (layer-2 out_b never consumed)
    const float *Wn1_ba = (const float*)d_in[21], *bn1_ba = (const float*)d_in[22], *Wr1_ba = (const float*)d_in[23];
    const float *W_out = (const float*)d_in[24], *b_out = (const float*)d_in[25];
    float* out = (float*)d_out;

    char* w = (char*)d_ws;
    size_t off = 0;
    auto alloc = [&](size_t b) -> char* {
        char* p = w + off;
        off += (b + 255) & ~(size_t)255;
        return p;
    };

    int* deg_aa = (int*)alloc(NA_N * 4);
    int* offs_aa = (int*)alloc((NA_N + 1) * 4);
    int* cur_aa = (int*)alloc(NA_N * 4);
    int* ss_aa = (int*)alloc((size_t)NE * 4);
    int* deg_ba = (int*)alloc(NA_N * 4);
    int* offs_ba = (int*)alloc((NA_N + 1) * 4);
    int* cur_ba = (int*)alloc(NA_N * 4);
    int* ss_ba = (int*)alloc((size_t)NE * 4);
    int* deg_ab = (int*)alloc(NB_N * 4);
    int* offs_ab = (int*)alloc((NB_N + 1) * 4);
    int* cur_ab = (int*)alloc(NB_N * 4);
    int* ss_ab = (int*)alloc((size_t)NE * 4);
    int* bsums = (int*)alloc(256 * 4);

    float* mean_aa = (float*)alloc((size_t)NA_N * DF * 4);
    float* mean_ba = (float*)alloc((size_t)NA_N * DF * 4);
    float* mean_ab = (float*)alloc((size_t)NB_N * DF * 4);  // layer2 reuses this as xa2
    float* xa1 = (float*)alloc((size_t)NA_N * DF * 4);
    float* xb1 = (float*)alloc((size_t)NB_N * DF * 4);
    float* xa2 = mean_ab;  // alias: mean_ab dead by the time xa2 is written
    float* wsum0 = (float*)alloc(DF * DF * 4);
    float* wsum1 = (float*)alloc(DF * DF * 4);
    float* pooled = (float*)alloc(NG_N * DF * 4);

    const int EBLK = (NE + 255) / 256;

    auto build_csr = [&](const int* ei, int ndst, int* deg, int* offs, int* cur, int* ss) {
        const int* srcp = ei;
        const int* dstp = ei + NE;
        hipMemsetAsync(deg, 0, (size_t)ndst * sizeof(int), stream);
        count_deg_k<<<EBLK, 256, 0, stream>>>(dstp, deg, NE);
        int nb = (ndst + 255) / 256;
        scan_block_k<<<nb, 256, 0, stream>>>(deg, ndst, offs, bsums);
        scan_sums_k<<<1, 256, 0, stream>>>(bsums, nb);
        add_base_k<<<nb, 256, 0, stream>>>(offs, bsums, ndst, cur, NE);
        fill_csr_k<<<EBLK, 256, 0, stream>>>(srcp, dstp, cur, ss, NE);
    };

    // CSRs (dst-indexed), built once, reused across both layers
    build_csr(ei_aa, NA_N, deg_aa, offs_aa, cur_aa, ss_aa);
    build_csr(ei_ba, NA_N, deg_ba, offs_ba, cur_ba, ss_ba);
    build_csr(ei_ab, NB_N, deg_ab, offs_ab, cur_ab, ss_ab);

    // Wr sums for the fused dst-a GEMM
    add_mats_k<<<(DF * DF + 255) / 256, 256, 0, stream>>>(Wr0_aa, Wr0_ba, wsum0, DF * DF);
    add_mats_k<<<(DF * DF + 255) / 256, 256, 0, stream>>>(Wr1_aa, Wr1_ba, wsum1, DF * DF);

    const int AGG_BLK_A = (NA_N * 64 + 255) / 256;
    const int AGG_BLK_B = (NB_N * 64 + 255) / 256;
    const int GEMM_BLK_A = (NA_N + 63) / 64;
    const int GEMM_BLK_B = (NB_N + 63) / 64;

    // ---- layer 0 ----
    aggregate_k<<<AGG_BLK_A, 256, 0, stream>>>(x_a, offs_aa, ss_aa, mean_aa, NA_N);
    aggregate_k<<<AGG_BLK_A, 256, 0, stream>>>(x_b, offs_ba, ss_ba, mean_ba, NA_N);
    aggregate_k<<<AGG_BLK_B, 256, 0, stream>>>(x_a, offs_ab, ss_ab, mean_ab, NB_N);
    gemm_fused_k<<<GEMM_BLK_A, 256, 0, stream>>>(
        mean_aa, Wn0_aa, mean_ba, Wn0_ba, x_a, wsum0,
        bn0_aa, bn0_ba, 3, NA_N, xa1);
    gemm_fused_k<<<GEMM_BLK_B, 256, 0, stream>>>(
        mean_ab, Wn0_ab, x_b, Wr0_ab, nullptr, nullptr,
        bn0_ab, nullptr, 2, NB_N, xb1);

    // ---- layer 1 (out_b unused downstream -> skipped) ----
    aggregate_k<<<AGG_BLK_A, 256, 0, stream>>>(xa1, offs_aa, ss_aa, mean_aa, NA_N);
    aggregate_k<<<AGG_BLK_A, 256, 0, stream>>>(xb1, offs_ba, ss_ba, mean_ba, NA_N);
    gemm_fused_k<<<GEMM_BLK_A, 256, 0, stream>>>(
        mean_aa, Wn1_aa, mean_ba, Wn1_ba, xa1, wsum1,
        bn1_aa, bn1_ba, 3, NA_N, xa2);

    // ---- pool + head ----
    pool_sum_k<<<NG_N, DF, 0, stream>>>(xa2, batch, pooled);
    out_head_k<<<1, 640, 0, stream>>>(pooled, W_out, b_out, out);
}

// Round 2
// 1109.149 us; speedup vs baseline: 1.1510x; 1.1510x over previous
//
#include <hip/hip_runtime.h>

#define NA_N 50000
#define NB_N 50000
#define NE   1000000
#define DF   128
#define NG_N 64
#define NC_N 10

// ---------------- CSR build ----------------

__global__ void count_deg_k(const int* __restrict__ dst, int* __restrict__ deg, int n) {
    int i = blockIdx.x * 256 + threadIdx.x;
    if (i < n) atomicAdd(&deg[dst[i]], 1);
}

__global__ void scan_block_k(const int* __restrict__ deg, int n,
                             int* __restrict__ offs, int* __restrict__ bsums) {
    __shared__ int s[256];
    int t = threadIdx.x, i = blockIdx.x * 256 + t;
    int v = (i < n) ? deg[i] : 0;
    s[t] = v;
    __syncthreads();
    for (int d = 1; d < 256; d <<= 1) {
        int x = (t >= d) ? s[t - d] : 0;
        __syncthreads();
        if (t >= d) s[t] += x;
        __syncthreads();
    }
    if (i < n) offs[i] = s[t] - v;           // exclusive within block
    if (t == 255) bsums[blockIdx.x] = s[255]; // block total
}

__global__ void scan_sums_k(int* bsums, int nb) {
    __shared__ int s[256];
    int t = threadIdx.x;
    int v = (t < nb) ? bsums[t] : 0;
    s[t] = v;
    __syncthreads();
    for (int d = 1; d < 256; d <<= 1) {
        int x = (t >= d) ? s[t - d] : 0;
        __syncthreads();
        if (t >= d) s[t] += x;
        __syncthreads();
    }
    if (t < nb) bsums[t] = s[t] - v;          // exclusive
}

__global__ void add_base_k(int* __restrict__ offs, const int* __restrict__ bsums,
                           int n, int* __restrict__ cur, int total) {
    int i = blockIdx.x * 256 + threadIdx.x;
    if (i < n) {
        int v = offs[i] + bsums[i >> 8];
        offs[i] = v;
        cur[i] = v;
    }
    if (i == 0) offs[n] = total;
}

__global__ void fill_csr_k(const int* __restrict__ src, const int* __restrict__ dst,
                           int* __restrict__ cur, int* __restrict__ ss, int n) {
    int i = blockIdx.x * 256 + threadIdx.x;
    if (i < n) {
        int p = atomicAdd(&cur[dst[i]], 1);
        ss[p] = src[i];
    }
}

// ---------------- segment mean (gather side, 1 wave per dst node) ----------------

__global__ __launch_bounds__(256) void aggregate_k(
    const float* __restrict__ xs, const int* __restrict__ offs,
    const int* __restrict__ ss, float* __restrict__ mean, int ndst) {
    int node = (blockIdx.x * 256 + threadIdx.x) >> 6;
    int lane = threadIdx.x & 63;
    if (node >= ndst) return;
    int o0 = offs[node], o1 = offs[node + 1];
    const float2* x2 = (const float2*)xs;
    float ax = 0.f, ay = 0.f;
    int e = o0;
    for (; e + 1 < o1; e += 2) {
        int s0 = ss[e], s1 = ss[e + 1];
        float2 v0 = x2[s0 * 64 + lane];
        float2 v1 = x2[s1 * 64 + lane];
        ax += v0.x + v1.x;
        ay += v0.y + v1.y;
    }
    if (e < o1) {
        float2 v = x2[ss[e] * 64 + lane];
        ax += v.x;
        ay += v.y;
    }
    int cnt = o1 - o0;
    float inv = 1.0f / (float)(cnt > 0 ? cnt : 1);
    float2 r;
    r.x = ax * inv;
    r.y = ay * inv;
    ((float2*)mean)[node * 64 + lane] = r;
}

// ---------------- fused multi-matrix GEMM: out = relu(sum_m A_m @ W_m + b0 [+ b1]) ----------------

__global__ __launch_bounds__(256) void gemm_fused_k(
    const float* __restrict__ A0, const float* __restrict__ W0,
    const float* __restrict__ A1, const float* __restrict__ W1,
    const float* __restrict__ A2, const float* __restrict__ W2,
    const float* __restrict__ b0, const float* __restrict__ b1,
    int nmats, int nrows, float* __restrict__ out) {
    __shared__ float As[64 * 20];   // stride 20 -> max 2-way bank aliasing (free)
    __shared__ float Ws[16 * 128];
    int tid = threadIdx.x;
    int tx = tid & 15, ty = tid >> 4;
    int row0 = blockIdx.x * 64;

    float acc[4][8];
#pragma unroll
    for (int i = 0; i < 4; i++)
#pragma unroll
        for (int j = 0; j < 8; j++) acc[i][j] = 0.f;

    for (int m = 0; m < nmats; m++) {
        const float* A = (m == 0) ? A0 : ((m == 1) ? A1 : A2);
        const float* W = (m == 0) ? W0 : ((m == 1) ? W1 : W2);
        for (int k0 = 0; k0 < DF; k0 += 16) {
            int r = tid >> 2, kk = (tid & 3) << 2;
            int row = row0 + r;
            if (row >= nrows) row = nrows - 1;
            float4 av = *(const float4*)(A + (size_t)row * DF + k0 + kk);
            int wk = tid >> 4, wc = (tid & 15) * 8;
            float4 wv0 = *(const float4*)(W + (k0 + wk) * DF + wc);
            float4 wv1 = *(const float4*)(W + (k0 + wk) * DF + wc + 4);
            __syncthreads();   // previous tile's reads done
            *(float4*)(As + r * 20 + kk) = av;
            *(float4*)(Ws + wk * 128 + wc) = wv0;
            *(float4*)(Ws + wk * 128 + wc + 4) = wv1;
            __syncthreads();
#pragma unroll
            for (int k = 0; k < 16; k++) {
                float a0 = As[(ty * 4 + 0) * 20 + k];
                float a1 = As[(ty * 4 + 1) * 20 + k];
                float a2 = As[(ty * 4 + 2) * 20 + k];
                float a3 = As[(ty * 4 + 3) * 20 + k];
                float4 w0 = *(const float4*)(Ws + k * 128 + tx * 8);
                float4 w1 = *(const float4*)(Ws + k * 128 + tx * 8 + 4);
                float wv[8] = {w0.x, w0.y, w0.z, w0.w, w1.x, w1.y, w1.z, w1.w};
                float av4[4] = {a0, a1, a2, a3};
#pragma unroll
                for (int i = 0; i < 4; i++)
#pragma unroll
                    for (int j = 0; j < 8; j++) acc[i][j] += av4[i] * wv[j];
            }
        }
    }

    float bj[8];
#pragma unroll
    for (int j = 0; j < 8; j++) {
        int c = tx * 8 + j;
        float bb = b0[c];
        if (b1) bb += b1[c];
        bj[j] = bb;
    }
#pragma unroll
    for (int i = 0; i < 4; i++) {
        int row = row0 + ty * 4 + i;
        if (row < nrows) {
            float4 o0, o1;
            o0.x = fmaxf(acc[i][0] + bj[0], 0.f);
            o0.y = fmaxf(acc[i][1] + bj[1], 0.f);
            o0.z = fmaxf(acc[i][2] + bj[2], 0.f);
            o0.w = fmaxf(acc[i][3] + bj[3], 0.f);
            o1.x = fmaxf(acc[i][4] + bj[4], 0.f);
            o1.y = fmaxf(acc[i][5] + bj[5], 0.f);
            o1.z = fmaxf(acc[i][6] + bj[6], 0.f);
            o1.w = fmaxf(acc[i][7] + bj[7], 0.f);
            *(float4*)(out + (size_t)row * DF + tx * 8) = o0;
            *(float4*)(out + (size_t)row * DF + tx * 8 + 4) = o1;
        }
    }
}

// ---------------- misc small kernels ----------------

__global__ void add_mats_k(const float* __restrict__ a, const float* __restrict__ b,
                           float* __restrict__ o, int n) {
    int i = blockIdx.x * 256 + threadIdx.x;
    if (i < n) o[i] = a[i] + b[i];
}

__device__ __forceinline__ int lb_search(const int* a, int n, int v) {
    int lo = 0, hi = n;
    while (lo < hi) {
        int m = (lo + hi) >> 1;
        if (a[m] < v) lo = m + 1; else hi = m;
    }
    return lo;
}

// Parallel pooling phase 1: each block scans 128 sorted rows; per-column
// running sum in a register, atomicAdd flush only at graph boundaries.
// ~391 blocks * 256 thr -> ~106K atomics over 8192 addresses (low contention).
__global__ __launch_bounds__(256) void pool_partial_k(
    const float* __restrict__ xa, const int* __restrict__ batch,
    float* __restrict__ pooled) {
    int col = threadIdx.x & 127;
    int half = threadIdx.x >> 7;            // 0 or 1
    int row0 = blockIdx.x * 128;
    int rend = row0 + 128;
    if (rend > NA_N) rend = NA_N;
    float acc = 0.f;
    int cur_g = -1;
    for (int r = row0 + half; r < rend; r += 2) {
        int g = batch[r];
        if (g != cur_g) {
            if (cur_g >= 0) atomicAdd(&pooled[cur_g * DF + col], acc);
            cur_g = g;
            acc = 0.f;
        }
        acc += xa[(size_t)r * DF + col];
    }
    if (cur_g >= 0) atomicAdd(&pooled[cur_g * DF + col], acc);
}

// Head: divides pooled sum by per-graph count (binary search over sorted batch)
__global__ void out_head_k(const float* __restrict__ pooled, const int* __restrict__ batch,
                           const float* __restrict__ Wout, const float* __restrict__ bout,
                           float* __restrict__ out) {
    int tid = threadIdx.x;
    if (tid >= NG_N * NC_N) return;
    int g = tid / NC_N, c = tid % NC_N;
    int lo = lb_search(batch, NA_N, g);
    int hi = lb_search(batch, NA_N, g + 1);
    int cnt = hi - lo;
    float inv = 1.0f / (float)(cnt > 0 ? cnt : 1);
    float s = 0.f;
    for (int k = 0; k < DF; k++) s += pooled[g * DF + k] * Wout[k * NC_N + c];
    out[tid] = s * inv + bout[c];
}

// ---------------- launcher ----------------

extern "C" void kernel_launch(void* const* d_in, const int* in_sizes, int n_in,
                              void* d_out, int out_size, void* d_ws, size_t ws_size,
                              hipStream_t stream) {
    const float* x_a = (const float*)d_in[0];
    const float* x_b = (const float*)d_in[1];
    const int* ei_aa = (const int*)d_in[2];
    const int* ei_ab = (const int*)d_in[3];
    const int* ei_ba = (const int*)d_in[4];
    const int* batch = (const int*)d_in[5];
    const float *Wn0_aa = (const float*)d_in[6],  *bn0_aa = (const float*)d_in[7],  *Wr0_aa = (const float*)d_in[8];
    const float *Wn0_ab = (const float*)d_in[9],  *bn0_ab = (const float*)d_in[10], *Wr0_ab = (const float*)d_in[11];
    const float *Wn0_ba = (const float*)d_in[12], *bn0_ba = (const float*)d_in[13], *Wr0_ba = (const float*)d_in[14];
    const float *Wn1_aa = (const float*)d_in[15], *bn1_aa = (const float*)d_in[16], *Wr1_aa = (const float*)d_in[17];
    // d_in[18..20] = Wn1_ab, bn1_ab, Wr1_ab — unused (layer-2 out_b never consumed)
    const float *Wn1_ba = (const float*)d_in[21], *bn1_ba = (const float*)d_in[22], *Wr1_ba = (const float*)d_in[23];
    const float *W_out = (const float*)d_in[24], *b_out = (const float*)d_in[25];
    float* out = (float*)d_out;

    char* w = (char*)d_ws;
    size_t off = 0;
    auto alloc = [&](size_t b) -> char* {
        char* p = w + off;
        off += (b + 255) & ~(size_t)255;
        return p;
    };

    int* deg_aa = (int*)alloc(NA_N * 4);
    int* offs_aa = (int*)alloc((NA_N + 1) * 4);
    int* cur_aa = (int*)alloc(NA_N * 4);
    int* ss_aa = (int*)alloc((size_t)NE * 4);
    int* deg_ba = (int*)alloc(NA_N * 4);
    int* offs_ba = (int*)alloc((NA_N + 1) * 4);
    int* cur_ba = (int*)alloc(NA_N * 4);
    int* ss_ba = (int*)alloc((size_t)NE * 4);
    int* deg_ab = (int*)alloc(NB_N * 4);
    int* offs_ab = (int*)alloc((NB_N + 1) * 4);
    int* cur_ab = (int*)alloc(NB_N * 4);
    int* ss_ab = (int*)alloc((size_t)NE * 4);
    int* bsums = (int*)alloc(256 * 4);

    float* mean_aa = (float*)alloc((size_t)NA_N * DF * 4);
    float* mean_ba = (float*)alloc((size_t)NA_N * DF * 4);
    float* mean_ab = (float*)alloc((size_t)NB_N * DF * 4);  // layer2 reuses this as xa2
    float* xa1 = (float*)alloc((size_t)NA_N * DF * 4);
    float* xb1 = (float*)alloc((size_t)NB_N * DF * 4);
    float* xa2 = mean_ab;  // alias: mean_ab dead by the time xa2 is written
    float* wsum0 = (float*)alloc(DF * DF * 4);
    float* wsum1 = (float*)alloc(DF * DF * 4);
    float* pooled = (float*)alloc(NG_N * DF * 4);

    const int EBLK = (NE + 255) / 256;

    auto build_csr = [&](const int* ei, int ndst, int* deg, int* offs, int* cur, int* ss) {
        const int* srcp = ei;
        const int* dstp = ei + NE;
        hipMemsetAsync(deg, 0, (size_t)ndst * sizeof(int), stream);
        count_deg_k<<<EBLK, 256, 0, stream>>>(dstp, deg, NE);
        int nb = (ndst + 255) / 256;
        scan_block_k<<<nb, 256, 0, stream>>>(deg, ndst, offs, bsums);
        scan_sums_k<<<1, 256, 0, stream>>>(bsums, nb);
        add_base_k<<<nb, 256, 0, stream>>>(offs, bsums, ndst, cur, NE);
        fill_csr_k<<<EBLK, 256, 0, stream>>>(srcp, dstp, cur, ss, NE);
    };

    // CSRs (dst-indexed), built once, reused across both layers
    build_csr(ei_aa, NA_N, deg_aa, offs_aa, cur_aa, ss_aa);
    build_csr(ei_ba, NA_N, deg_ba, offs_ba, cur_ba, ss_ba);
    build_csr(ei_ab, NB_N, deg_ab, offs_ab, cur_ab, ss_ab);

    // Wr sums for the fused dst-a GEMM
    add_mats_k<<<(DF * DF + 255) / 256, 256, 0, stream>>>(Wr0_aa, Wr0_ba, wsum0, DF * DF);
    add_mats_k<<<(DF * DF + 255) / 256, 256, 0, stream>>>(Wr1_aa, Wr1_ba, wsum1, DF * DF);

    const int AGG_BLK_A = (NA_N * 64 + 255) / 256;
    const int AGG_BLK_B = (NB_N * 64 + 255) / 256;
    const int GEMM_BLK_A = (NA_N + 63) / 64;
    const int GEMM_BLK_B = (NB_N + 63) / 64;

    // ---- layer 0 ----
    aggregate_k<<<AGG_BLK_A, 256, 0, stream>>>(x_a, offs_aa, ss_aa, mean_aa, NA_N);
    aggregate_k<<<AGG_BLK_A, 256, 0, stream>>>(x_b, offs_ba, ss_ba, mean_ba, NA_N);
    aggregate_k<<<AGG_BLK_B, 256, 0, stream>>>(x_a, offs_ab, ss_ab, mean_ab, NB_N);
    gemm_fused_k<<<GEMM_BLK_A, 256, 0, stream>>>(
        mean_aa, Wn0_aa, mean_ba, Wn0_ba, x_a, wsum0,
        bn0_aa, bn0_ba, 3, NA_N, xa1);
    gemm_fused_k<<<GEMM_BLK_B, 256, 0, stream>>>(
        mean_ab, Wn0_ab, x_b, Wr0_ab, nullptr, nullptr,
        bn0_ab, nullptr, 2, NB_N, xb1);

    // ---- layer 1 (out_b unused downstream -> skipped) ----
    aggregate_k<<<AGG_BLK_A, 256, 0, stream>>>(xa1, offs_aa, ss_aa, mean_aa, NA_N);
    aggregate_k<<<AGG_BLK_A, 256, 0, stream>>>(xb1, offs_ba, ss_ba, mean_ba, NA_N);
    gemm_fused_k<<<GEMM_BLK_A, 256, 0, stream>>>(
        mean_aa, Wn1_aa, mean_ba, Wn1_ba, xa1, wsum1,
        bn1_aa, bn1_ba, 3, NA_N, xa2);

    // ---- pool + head ----
    hipMemsetAsync(pooled, 0, (size_t)NG_N * DF * sizeof(float), stream);
    pool_partial_k<<<(NA_N + 127) / 128, 256, 0, stream>>>(xa2, batch, pooled);
    out_head_k<<<1, 640, 0, stream>>>(pooled, batch, W_out, b_out, out);
}

// Round 3
// 854.517 us; speedup vs baseline: 1.4940x; 1.2980x over previous
//
#include <hip/hip_runtime.h>

#define NA_N 50000
#define NB_N 50000
#define NE   1000000
#define DF   128
#define NG_N 64
#define NC_N 10

typedef __attribute__((ext_vector_type(8))) short short8;
typedef __attribute__((ext_vector_type(8))) unsigned short ushort8;
typedef __attribute__((ext_vector_type(4))) float float4v;

__device__ __forceinline__ unsigned short f2bf(float f) {
    unsigned u = __float_as_uint(f);
    unsigned r = (u + 0x7fff + ((u >> 16) & 1)) >> 16;   // RNE
    return (unsigned short)r;
}
__device__ __forceinline__ float bf2f(unsigned short b) {
    return __uint_as_float(((unsigned)b) << 16);
}

// ---------------- fp32 -> bf16 convert ----------------

__global__ void convert_bf_k(const float* __restrict__ x, unsigned short* __restrict__ y, int n4) {
    int i = blockIdx.x * 256 + threadIdx.x;
    if (i < n4) {
        float4 v = ((const float4*)x)[i];
        ushort4 o;
        o.x = f2bf(v.x); o.y = f2bf(v.y); o.z = f2bf(v.z); o.w = f2bf(v.w);
        ((ushort4*)y)[i] = o;
    }
}

// ---------------- weight -> B-fragment order (bf16) ----------------
// Wf linear index t = ((n0*4 + k0i)*64 + lane)*8 + j
// holds W[k0i*32 + (lane>>4)*8 + j][n0*16 + (lane&15)]  (optionally Wa+Wb)

__global__ void prearrange_w_k(const float* __restrict__ Wa, const float* __restrict__ Wb,
                               unsigned short* __restrict__ dst) {
    int t = blockIdx.x * 256 + threadIdx.x;      // 0..16383
    int j = t & 7, lane = (t >> 3) & 63, k0i = (t >> 9) & 3, n0 = t >> 11;
    int k = k0i * 32 + (lane >> 4) * 8 + j;
    int n = n0 * 16 + (lane & 15);
    float v = Wa[k * DF + n];
    if (Wb) v += Wb[k * DF + n];
    dst[t] = f2bf(v);
}

// ---------------- CSR build ----------------

__global__ void count_deg_k(const int* __restrict__ dst, int* __restrict__ deg, int n) {
    int i = blockIdx.x * 256 + threadIdx.x;
    if (i < n) atomicAdd(&deg[dst[i]], 1);
}

__global__ void scan_block_k(const int* __restrict__ deg, int n,
                             int* __restrict__ offs, int* __restrict__ bsums) {
    __shared__ int s[256];
    int t = threadIdx.x, i = blockIdx.x * 256 + t;
    int v = (i < n) ? deg[i] : 0;
    s[t] = v;
    __syncthreads();
    for (int d = 1; d < 256; d <<= 1) {
        int x = (t >= d) ? s[t - d] : 0;
        __syncthreads();
        if (t >= d) s[t] += x;
        __syncthreads();
    }
    if (i < n) offs[i] = s[t] - v;
    if (t == 255) bsums[blockIdx.x] = s[255];
}

__global__ void scan_sums_k(int* bsums, int nb) {
    __shared__ int s[256];
    int t = threadIdx.x;
    int v = (t < nb) ? bsums[t] : 0;
    s[t] = v;
    __syncthreads();
    for (int d = 1; d < 256; d <<= 1) {
        int x = (t >= d) ? s[t - d] : 0;
        __syncthreads();
        if (t >= d) s[t] += x;
        __syncthreads();
    }
    if (t < nb) bsums[t] = s[t] - v;
}

__global__ void add_base_k(int* __restrict__ offs, const int* __restrict__ bsums,
                           int n, int* __restrict__ cur, int total) {
    int i = blockIdx.x * 256 + threadIdx.x;
    if (i < n) {
        int v = offs[i] + bsums[i >> 8];
        offs[i] = v;
        cur[i] = v;
    }
    if (i == 0) offs[n] = total;
}

__global__ void fill_csr_k(const int* __restrict__ src, const int* __restrict__ dst,
                           int* __restrict__ cur, int* __restrict__ ss, int n) {
    int i = blockIdx.x * 256 + threadIdx.x;
    if (i < n) {
        int p = atomicAdd(&cur[dst[i]], 1);
        ss[p] = src[i];
    }
}

// ---------------- segment mean, bf16 gather (1 wave / dst node, 4 edges / iter) ----------------

__global__ __launch_bounds__(256) void aggregate_bf_k(
    const unsigned short* __restrict__ xs, const int* __restrict__ offs,
    const int* __restrict__ ss, unsigned short* __restrict__ mean, int ndst) {
    int node = (blockIdx.x * 256 + threadIdx.x) >> 6;
    int lane = threadIdx.x & 63;
    if (node >= ndst) return;
    int o0 = offs[node], o1 = offs[node + 1];
    int sub = lane >> 4;     // which edge of the group of 4
    int q = lane & 15;       // 16 lanes per row, 8 bf16 each
    float acc[8] = {0.f, 0.f, 0.f, 0.f, 0.f, 0.f, 0.f, 0.f};
    for (int e = o0 + sub; e < o1; e += 4) {
        int s = ss[e];
        ushort8 v = *(const ushort8*)(xs + (size_t)s * DF + q * 8);
#pragma unroll
        for (int j = 0; j < 8; j++) acc[j] += bf2f(v[j]);
    }
#pragma unroll
    for (int j = 0; j < 8; j++) {
        acc[j] += __shfl_down(acc[j], 32, 64);
        acc[j] += __shfl_down(acc[j], 16, 64);
    }
    if (sub == 0) {
        int cnt = o1 - o0;
        float inv = 1.0f / (float)(cnt > 0 ? cnt : 1);
        ushort4 r0, r1;
        r0.x = f2bf(acc[0] * inv); r0.y = f2bf(acc[1] * inv);
        r0.z = f2bf(acc[2] * inv); r0.w = f2bf(acc[3] * inv);
        r1.x = f2bf(acc[4] * inv); r1.y = f2bf(acc[5] * inv);
        r1.z = f2bf(acc[6] * inv); r1.w = f2bf(acc[7] * inv);
        *(ushort4*)(mean + (size_t)node * DF + q * 8) = r0;
        *(ushort4*)(mean + (size_t)node * DF + q * 8 + 4) = r1;
    }
}

// ---------------- bf16 MFMA GEMM: out = relu(sum_m A_m @ W_m + b0 [+ b1]) ----------------
// A: bf16 [nrows,128] row-major; Wf: prearranged B-fragment order; out: bf16.
// Block = 4 waves; wave does 32 rows x 128 cols. No LDS.

__global__ __launch_bounds__(256) void gemm_mfma_k(
    const unsigned short* __restrict__ A0, const unsigned short* __restrict__ Wf0,
    const unsigned short* __restrict__ A1, const unsigned short* __restrict__ Wf1,
    const unsigned short* __restrict__ A2, const unsigned short* __restrict__ Wf2,
    const float* __restrict__ b0, const float* __restrict__ b1,
    int nmats, int nrows, unsigned short* __restrict__ out) {
    int lane = threadIdx.x & 63;
    int wv = threadIdx.x >> 6;
    int r0 = blockIdx.x * 128 + wv * 32;
    int m = lane & 15, quad = lane >> 4;
    int rowA = r0 + m;      if (rowA >= nrows) rowA = nrows - 1;
    int rowB = r0 + 16 + m; if (rowB >= nrows) rowB = nrows - 1;

    float4v acc0[8], acc1[8];
#pragma unroll
    for (int n0 = 0; n0 < 8; n0++) {
        acc0[n0] = (float4v){0.f, 0.f, 0.f, 0.f};
        acc1[n0] = (float4v){0.f, 0.f, 0.f, 0.f};
    }

    for (int mat = 0; mat < nmats; mat++) {
        const unsigned short* A  = (mat == 0) ? A0  : ((mat == 1) ? A1  : A2);
        const unsigned short* Wf = (mat == 0) ? Wf0 : ((mat == 1) ? Wf1 : Wf2);
#pragma unroll
        for (int k0i = 0; k0i < 4; k0i++) {
            short8 a0 = *(const short8*)(A + (size_t)rowA * DF + k0i * 32 + quad * 8);
            short8 a1 = *(const short8*)(A + (size_t)rowB * DF + k0i * 32 + quad * 8);
#pragma unroll
            for (int n0 = 0; n0 < 8; n0++) {
                short8 b = *(const short8*)(Wf + (((n0 * 4 + k0i) * 64 + lane) << 3));
                acc0[n0] = __builtin_amdgcn_mfma_f32_16x16x32_bf16(a0, b, acc0[n0], 0, 0, 0);
                acc1[n0] = __builtin_amdgcn_mfma_f32_16x16x32_bf16(a1, b, acc1[n0], 0, 0, 0);
            }
        }
    }

    // epilogue: C/D layout col=lane&15, row=quad*4+reg (m89-verified)
#pragma unroll
    for (int n0 = 0; n0 < 8; n0++) {
        int c = n0 * 16 + m;
        float bb = b0[c] + (b1 ? b1[c] : 0.f);
#pragma unroll
        for (int i = 0; i < 4; i++) {
            int r = r0 + quad * 4 + i;
            if (r < nrows) out[(size_t)r * DF + c] = f2bf(fmaxf(acc0[n0][i] + bb, 0.f));
            int r2 = r0 + 16 + quad * 4 + i;
            if (r2 < nrows) out[(size_t)r2 * DF + c] = f2bf(fmaxf(acc1[n0][i] + bb, 0.f));
        }
    }
}

// ---------------- pooling + head ----------------

__device__ __forceinline__ int lb_search(const int* a, int n, int v) {
    int lo = 0, hi = n;
    while (lo < hi) {
        int mm = (lo + hi) >> 1;
        if (a[mm] < v) lo = mm + 1; else hi = mm;
    }
    return lo;
}

__global__ __launch_bounds__(256) void pool_partial_k(
    const unsigned short* __restrict__ xa, const int* __restrict__ batch,
    float* __restrict__ pooled) {
    int col = threadIdx.x & 127;
    int half = threadIdx.x >> 7;
    int row0 = blockIdx.x * 128;
    int rend = row0 + 128;
    if (rend > NA_N) rend = NA_N;
    float acc = 0.f;
    int cur_g = -1;
    for (int r = row0 + half; r < rend; r += 2) {
        int g = batch[r];
        if (g != cur_g) {
            if (cur_g >= 0) atomicAdd(&pooled[cur_g * DF + col], acc);
            cur_g = g;
            acc = 0.f;
        }
        acc += bf2f(xa[(size_t)r * DF + col]);
    }
    if (cur_g >= 0) atomicAdd(&pooled[cur_g * DF + col], acc);
}

__global__ void out_head_k(const float* __restrict__ pooled, const int* __restrict__ batch,
                           const float* __restrict__ Wout, const float* __restrict__ bout,
                           float* __restrict__ out) {
    int tid = threadIdx.x;
    if (tid >= NG_N * NC_N) return;
    int g = tid / NC_N, c = tid % NC_N;
    int lo = lb_search(batch, NA_N, g);
    int hi = lb_search(batch, NA_N, g + 1);
    int cnt = hi - lo;
    float inv = 1.0f / (float)(cnt > 0 ? cnt : 1);
    float s = 0.f;
    for (int k = 0; k < DF; k++) s += pooled[g * DF + k] * Wout[k * NC_N + c];
    out[tid] = s * inv + bout[c];
}

// ---------------- launcher ----------------

extern "C" void kernel_launch(void* const* d_in, const int* in_sizes, int n_in,
                              void* d_out, int out_size, void* d_ws, size_t ws_size,
                              hipStream_t stream) {
    const float* x_a = (const float*)d_in[0];
    const float* x_b = (const float*)d_in[1];
    const int* ei_aa = (const int*)d_in[2];
    const int* ei_ab = (const int*)d_in[3];
    const int* ei_ba = (const int*)d_in[4];
    const int* batch = (const int*)d_in[5];
    const float *Wn0_aa = (const float*)d_in[6],  *bn0_aa = (const float*)d_in[7],  *Wr0_aa = (const float*)d_in[8];
    const float *Wn0_ab = (const float*)d_in[9],  *bn0_ab = (const float*)d_in[10], *Wr0_ab = (const float*)d_in[11];
    const float *Wn0_ba = (const float*)d_in[12], *bn0_ba = (const float*)d_in[13], *Wr0_ba = (const float*)d_in[14];
    const float *Wn1_aa = (const float*)d_in[15], *bn1_aa = (const float*)d_in[16], *Wr1_aa = (const float*)d_in[17];
    // d_in[18..20] unused (layer-2 out_b never consumed)
    const float *Wn1_ba = (const float*)d_in[21], *bn1_ba = (const float*)d_in[22], *Wr1_ba = (const float*)d_in[23];
    const float *W_out = (const float*)d_in[24], *b_out = (const float*)d_in[25];
    float* out = (float*)d_out;

    char* w = (char*)d_ws;
    size_t off = 0;
    auto alloc = [&](size_t b) -> char* {
        char* p = w + off;
        off += (b + 255) & ~(size_t)255;
        return p;
    };

    int* deg_aa = (int*)alloc(NA_N * 4);
    int* offs_aa = (int*)alloc((NA_N + 1) * 4);
    int* cur_aa = (int*)alloc(NA_N * 4);
    int* ss_aa = (int*)alloc((size_t)NE * 4);
    int* deg_ba = (int*)alloc(NA_N * 4);
    int* offs_ba = (int*)alloc((NA_N + 1) * 4);
    int* cur_ba = (int*)alloc(NA_N * 4);
    int* ss_ba = (int*)alloc((size_t)NE * 4);
    int* deg_ab = (int*)alloc(NB_N * 4);
    int* offs_ab = (int*)alloc((NB_N + 1) * 4);
    int* cur_ab = (int*)alloc(NB_N * 4);
    int* ss_ab = (int*)alloc((size_t)NE * 4);
    int* bsums = (int*)alloc(256 * 4);

    unsigned short* xa_bf  = (unsigned short*)alloc((size_t)NA_N * DF * 2);
    unsigned short* xb_bf  = (unsigned short*)alloc((size_t)NB_N * DF * 2);
    unsigned short* mean_aa = (unsigned short*)alloc((size_t)NA_N * DF * 2);
    unsigned short* mean_ba = (unsigned short*)alloc((size_t)NA_N * DF * 2);
    unsigned short* mean_ab = (unsigned short*)alloc((size_t)NB_N * DF * 2);
    unsigned short* xa1 = (unsigned short*)alloc((size_t)NA_N * DF * 2);
    unsigned short* xb1 = (unsigned short*)alloc((size_t)NB_N * DF * 2);
    unsigned short* xa2 = mean_ab;  // alias: mean_ab dead once layer-0 dst-b GEMM ran
    unsigned short* Wf[8];
    for (int i = 0; i < 8; i++) Wf[i] = (unsigned short*)alloc((size_t)DF * DF * 2);
    float* pooled = (float*)alloc(NG_N * DF * 4);

    const int EBLK = (NE + 255) / 256;

    auto build_csr = [&](const int* ei, int ndst, int* deg, int* offs, int* cur, int* ss) {
        const int* srcp = ei;
        const int* dstp = ei + NE;
        hipMemsetAsync(deg, 0, (size_t)ndst * sizeof(int), stream);
        count_deg_k<<<EBLK, 256, 0, stream>>>(dstp, deg, NE);
        int nb = (ndst + 255) / 256;
        scan_block_k<<<nb, 256, 0, stream>>>(deg, ndst, offs, bsums);
        scan_sums_k<<<1, 256, 0, stream>>>(bsums, nb);
        add_base_k<<<nb, 256, 0, stream>>>(offs, bsums, ndst, cur, NE);
        fill_csr_k<<<EBLK, 256, 0, stream>>>(srcp, dstp, cur, ss, NE);
    };

    build_csr(ei_aa, NA_N, deg_aa, offs_aa, cur_aa, ss_aa);
    build_csr(ei_ba, NA_N, deg_ba, offs_ba, cur_ba, ss_ba);
    build_csr(ei_ab, NB_N, deg_ab, offs_ab, cur_ab, ss_ab);

    // feature conversion fp32 -> bf16
    const int CN4 = NA_N * DF / 4;
    convert_bf_k<<<(CN4 + 255) / 256, 256, 0, stream>>>(x_a, xa_bf, CN4);
    convert_bf_k<<<(CN4 + 255) / 256, 256, 0, stream>>>(x_b, xb_bf, CN4);

    // weights -> fragment order (Wr pairs summed here)
    prearrange_w_k<<<64, 256, 0, stream>>>(Wn0_aa, nullptr, Wf[0]);
    prearrange_w_k<<<64, 256, 0, stream>>>(Wn0_ba, nullptr, Wf[1]);
    prearrange_w_k<<<64, 256, 0, stream>>>(Wr0_aa, Wr0_ba, Wf[2]);
    prearrange_w_k<<<64, 256, 0, stream>>>(Wn0_ab, nullptr, Wf[3]);
    prearrange_w_k<<<64, 256, 0, stream>>>(Wr0_ab, nullptr, Wf[4]);
    prearrange_w_k<<<64, 256, 0, stream>>>(Wn1_aa, nullptr, Wf[5]);
    prearrange_w_k<<<64, 256, 0, stream>>>(Wn1_ba, nullptr, Wf[6]);
    prearrange_w_k<<<64, 256, 0, stream>>>(Wr1_aa, Wr1_ba, Wf[7]);

    const int AGG_BLK_A = (NA_N * 64 + 255) / 256;
    const int AGG_BLK_B = (NB_N * 64 + 255) / 256;
    const int GEMM_BLK_A = (NA_N + 127) / 128;
    const int GEMM_BLK_B = (NB_N + 127) / 128;

    // ---- layer 0 ----
    aggregate_bf_k<<<AGG_BLK_A, 256, 0, stream>>>(xa_bf, offs_aa, ss_aa, mean_aa, NA_N);
    aggregate_bf_k<<<AGG_BLK_A, 256, 0, stream>>>(xb_bf, offs_ba, ss_ba, mean_ba, NA_N);
    aggregate_bf_k<<<AGG_BLK_B, 256, 0, stream>>>(xa_bf, offs_ab, ss_ab, mean_ab, NB_N);
    gemm_mfma_k<<<GEMM_BLK_A, 256, 0, stream>>>(
        mean_aa, Wf[0], mean_ba, Wf[1], xa_bf, Wf[2],
        bn0_aa, bn0_ba, 3, NA_N, xa1);
    gemm_mfma_k<<<GEMM_BLK_B, 256, 0, stream>>>(
        mean_ab, Wf[3], xb_bf, Wf[4], nullptr, nullptr,
        bn0_ab, nullptr, 2, NB_N, xb1);

    // ---- layer 1 (out_b unused downstream -> skipped) ----
    aggregate_bf_k<<<AGG_BLK_A, 256, 0, stream>>>(xa1, offs_aa, ss_aa, mean_aa, NA_N);
    aggregate_bf_k<<<AGG_BLK_A, 256, 0, stream>>>(xb1, offs_ba, ss_ba, mean_ba, NA_N);
    gemm_mfma_k<<<GEMM_BLK_A, 256, 0, stream>>>(
        mean_aa, Wf[5], mean_ba, Wf[6], xa1, Wf[7],
        bn1_aa, bn1_ba, 3, NA_N, xa2);

    // ---- pool + head ----
    hipMemsetAsync(pooled, 0, (size_t)NG_N * DF * sizeof(float), stream);
    pool_partial_k<<<(NA_N + 127) / 128, 256, 0, stream>>>(xa2, batch, pooled);
    out_head_k<<<1, 640, 0, stream>>>(pooled, batch, W_out, b_out, out);
}

// Round 4
// 633.063 us; speedup vs baseline: 2.0166x; 1.3498x over previous
//
#include <hip/hip_runtime.h>

#define NA_N 50000
#define NB_N 50000
#define NE   1000000
#define DF   128
#define NG_N 64
#define NC_N 10

// bucketed counting sort params
#define BSHIFT 7
#define BNODES 128                       // nodes per bucket
#define NBUK   391                       // ceil(50000/128)
#define CHB    4096                      // edges per binning block
#define NIT    (CHB / 256)               // 16 edges per thread

typedef __attribute__((ext_vector_type(8))) short short8;
typedef __attribute__((ext_vector_type(8))) unsigned short ushort8;
typedef __attribute__((ext_vector_type(4))) float float4v;

__device__ __forceinline__ unsigned short f2bf(float f) {
    unsigned u = __float_as_uint(f);
    unsigned r = (u + 0x7fff + ((u >> 16) & 1)) >> 16;   // RNE
    return (unsigned short)r;
}
__device__ __forceinline__ float bf2f(unsigned short b) {
    return __uint_as_float(((unsigned)b) << 16);
}

// ---------------- fp32 -> bf16 convert ----------------

__global__ void convert_bf_k(const float* __restrict__ x, unsigned short* __restrict__ y, int n4) {
    int i = blockIdx.x * 256 + threadIdx.x;
    if (i < n4) {
        float4 v = ((const float4*)x)[i];
        ushort4 o;
        o.x = f2bf(v.x); o.y = f2bf(v.y); o.z = f2bf(v.z); o.w = f2bf(v.w);
        ((ushort4*)y)[i] = o;
    }
}

// ---------------- weight -> B-fragment order (bf16) ----------------

__global__ void prearrange_w_k(const float* __restrict__ Wa, const float* __restrict__ Wb,
                               unsigned short* __restrict__ dst) {
    int t = blockIdx.x * 256 + threadIdx.x;      // 0..16383
    int j = t & 7, lane = (t >> 3) & 63, k0i = (t >> 9) & 3, n0 = t >> 11;
    int k = k0i * 32 + (lane >> 4) * 8 + j;
    int n = n0 * 16 + (lane & 15);
    float v = Wa[k * DF + n];
    if (Wb) v += Wb[k * DF + n];
    dst[t] = f2bf(v);
}

// ---------------- CSR build via two-level bucketed counting sort ----------------

// Pass A: bucket histogram (LDS-staged)
__global__ __launch_bounds__(256) void bucket_hist_k(const int* __restrict__ dst,
                                                     int* __restrict__ bcnt) {
    __shared__ int h[NBUK];
    for (int i = threadIdx.x; i < NBUK; i += 256) h[i] = 0;
    __syncthreads();
    int base = blockIdx.x * CHB;
#pragma unroll
    for (int it = 0; it < NIT; it++) {
        int i = base + it * 256 + threadIdx.x;
        if (i < NE) atomicAdd(&h[dst[i] >> BSHIFT], 1);
    }
    __syncthreads();
    for (int i = threadIdx.x; i < NBUK; i += 256)
        if (h[i]) atomicAdd(&bcnt[i], h[i]);
}

// Scan bucket counts -> bases + rolling cursors (1 block, 512 threads)
__global__ void bucket_scan_k(const int* __restrict__ bcnt,
                              int* __restrict__ bbase, int* __restrict__ bcur) {
    __shared__ int s[512];
    int t = threadIdx.x;
    int v = (t < NBUK) ? bcnt[t] : 0;
    s[t] = v;
    __syncthreads();
    for (int d = 1; d < 512; d <<= 1) {
        int x = (t >= d) ? s[t - d] : 0;
        __syncthreads();
        if (t >= d) s[t] += x;
        __syncthreads();
    }
    if (t < NBUK) {
        int e = s[t] - v;     // exclusive
        bbase[t] = e;
        bcur[t] = e;
    }
    if (t == 0) bbase[NBUK] = NE;
}

// Pass B: bin edges into bucket regions; packed word = (dst_local<<24) | src
__global__ __launch_bounds__(256) void bucket_bin_k(const int* __restrict__ src,
                                                    const int* __restrict__ dst,
                                                    int* __restrict__ bcur,
                                                    unsigned* __restrict__ ebuf) {
    __shared__ int cnt[NBUK];
    __shared__ int chunk[NBUK];
    for (int i = threadIdx.x; i < NBUK; i += 256) cnt[i] = 0;
    __syncthreads();
    int base = blockIdx.x * CHB;
    int bk[NIT], rk[NIT];
    unsigned sv[NIT];
#pragma unroll
    for (int it = 0; it < NIT; it++) {
        int i = base + it * 256 + threadIdx.x;
        if (i < NE) {
            int d = dst[i];
            int b = d >> BSHIFT;
            bk[it] = b;
            rk[it] = atomicAdd(&cnt[b], 1);
            sv[it] = (unsigned)src[i] | ((unsigned)(d & (BNODES - 1)) << 24);
        } else {
            bk[it] = -1;
        }
    }
    __syncthreads();
    for (int i = threadIdx.x; i < NBUK; i += 256)
        chunk[i] = cnt[i] ? atomicAdd(&bcur[i], cnt[i]) : 0;
    __syncthreads();
#pragma unroll
    for (int it = 0; it < NIT; it++)
        if (bk[it] >= 0) ebuf[chunk[bk[it]] + rk[it]] = sv[it];
}

// Pass C: per-bucket counting sort; emits final offs and sorted src list
__global__ __launch_bounds__(256) void bucket_sort_k(const unsigned* __restrict__ ebuf,
                                                     const int* __restrict__ bbase,
                                                     int* __restrict__ offs,
                                                     int* __restrict__ ss, int ndst) {
    __shared__ int hist[BNODES];
    __shared__ int loffs[BNODES];
    int b = blockIdx.x;
    int t = threadIdx.x;
    int ebase = bbase[b], ecnt = bbase[b + 1] - ebase;
    if (t < BNODES) hist[t] = 0;
    __syncthreads();
    for (int e = t; e < ecnt; e += 256)
        atomicAdd(&hist[ebuf[ebase + e] >> 24], 1);
    __syncthreads();
    if (t < BNODES) loffs[t] = hist[t];
    __syncthreads();
    for (int d = 1; d < BNODES; d <<= 1) {
        int x = 0;
        if (t < BNODES && t >= d) x = loffs[t - d];
        __syncthreads();
        if (t < BNODES && t >= d) loffs[t] += x;
        __syncthreads();
    }
    if (t < BNODES) {
        int ex = loffs[t] - hist[t];          // exclusive scan
        loffs[t] = ex;
        int gnode = b * BNODES + t;
        if (gnode < ndst) offs[gnode] = ebase + ex;
        hist[t] = 0;                           // reuse as placement cursor
    }
    if (b == 0 && t == 0) offs[ndst] = NE;
    __syncthreads();
    for (int e = t; e < ecnt; e += 256) {
        unsigned w = ebuf[ebase + e];
        int dl = w >> 24;
        int r = atomicAdd(&hist[dl], 1);
        ss[ebase + loffs[dl] + r] = (int)(w & 0xFFFFFF);
    }
}

// ---------------- segment mean, bf16 gather (1 wave / dst node, 4 edges / iter) ----------------

__global__ __launch_bounds__(256) void aggregate_bf_k(
    const unsigned short* __restrict__ xs, const int* __restrict__ offs,
    const int* __restrict__ ss, unsigned short* __restrict__ mean, int ndst) {
    int node = (blockIdx.x * 256 + threadIdx.x) >> 6;
    int lane = threadIdx.x & 63;
    if (node >= ndst) return;
    int o0 = offs[node], o1 = offs[node + 1];
    int sub = lane >> 4;
    int q = lane & 15;
    float acc[8] = {0.f, 0.f, 0.f, 0.f, 0.f, 0.f, 0.f, 0.f};
    for (int e = o0 + sub; e < o1; e += 4) {
        int s = ss[e];
        ushort8 v = *(const ushort8*)(xs + (size_t)s * DF + q * 8);
#pragma unroll
        for (int j = 0; j < 8; j++) acc[j] += bf2f(v[j]);
    }
#pragma unroll
    for (int j = 0; j < 8; j++) {
        acc[j] += __shfl_down(acc[j], 32, 64);
        acc[j] += __shfl_down(acc[j], 16, 64);
    }
    if (sub == 0) {
        int cnt = o1 - o0;
        float inv = 1.0f / (float)(cnt > 0 ? cnt : 1);
        ushort4 r0, r1;
        r0.x = f2bf(acc[0] * inv); r0.y = f2bf(acc[1] * inv);
        r0.z = f2bf(acc[2] * inv); r0.w = f2bf(acc[3] * inv);
        r1.x = f2bf(acc[4] * inv); r1.y = f2bf(acc[5] * inv);
        r1.z = f2bf(acc[6] * inv); r1.w = f2bf(acc[7] * inv);
        *(ushort4*)(mean + (size_t)node * DF + q * 8) = r0;
        *(ushort4*)(mean + (size_t)node * DF + q * 8 + 4) = r1;
    }
}

// ---------------- bf16 MFMA GEMM ----------------

__global__ __launch_bounds__(256) void gemm_mfma_k(
    const unsigned short* __restrict__ A0, const unsigned short* __restrict__ Wf0,
    const unsigned short* __restrict__ A1, const unsigned short* __restrict__ Wf1,
    const unsigned short* __restrict__ A2, const unsigned short* __restrict__ Wf2,
    const float* __restrict__ b0, const float* __restrict__ b1,
    int nmats, int nrows, unsigned short* __restrict__ out) {
    int lane = threadIdx.x & 63;
    int wv = threadIdx.x >> 6;
    int r0 = blockIdx.x * 128 + wv * 32;
    int m = lane & 15, quad = lane >> 4;
    int rowA = r0 + m;      if (rowA >= nrows) rowA = nrows - 1;
    int rowB = r0 + 16 + m; if (rowB >= nrows) rowB = nrows - 1;

    float4v acc0[8], acc1[8];
#pragma unroll
    for (int n0 = 0; n0 < 8; n0++) {
        acc0[n0] = (float4v){0.f, 0.f, 0.f, 0.f};
        acc1[n0] = (float4v){0.f, 0.f, 0.f, 0.f};
    }

    for (int mat = 0; mat < nmats; mat++) {
        const unsigned short* A  = (mat == 0) ? A0  : ((mat == 1) ? A1  : A2);
        const unsigned short* Wf = (mat == 0) ? Wf0 : ((mat == 1) ? Wf1 : Wf2);
#pragma unroll
        for (int k0i = 0; k0i < 4; k0i++) {
            short8 a0 = *(const short8*)(A + (size_t)rowA * DF + k0i * 32 + quad * 8);
            short8 a1 = *(const short8*)(A + (size_t)rowB * DF + k0i * 32 + quad * 8);
#pragma unroll
            for (int n0 = 0; n0 < 8; n0++) {
                short8 b = *(const short8*)(Wf + (((n0 * 4 + k0i) * 64 + lane) << 3));
                acc0[n0] = __builtin_amdgcn_mfma_f32_16x16x32_bf16(a0, b, acc0[n0], 0, 0, 0);
                acc1[n0] = __builtin_amdgcn_mfma_f32_16x16x32_bf16(a1, b, acc1[n0], 0, 0, 0);
            }
        }
    }

#pragma unroll
    for (int n0 = 0; n0 < 8; n0++) {
        int c = n0 * 16 + m;
        float bb = b0[c] + (b1 ? b1[c] : 0.f);
#pragma unroll
        for (int i = 0; i < 4; i++) {
            int r = r0 + quad * 4 + i;
            if (r < nrows) out[(size_t)r * DF + c] = f2bf(fmaxf(acc0[n0][i] + bb, 0.f));
            int r2 = r0 + 16 + quad * 4 + i;
            if (r2 < nrows) out[(size_t)r2 * DF + c] = f2bf(fmaxf(acc1[n0][i] + bb, 0.f));
        }
    }
}

// ---------------- pooling + head ----------------

__device__ __forceinline__ int lb_search(const int* a, int n, int v) {
    int lo = 0, hi = n;
    while (lo < hi) {
        int mm = (lo + hi) >> 1;
        if (a[mm] < v) lo = mm + 1; else hi = mm;
    }
    return lo;
}

__global__ __launch_bounds__(256) void pool_partial_k(
    const unsigned short* __restrict__ xa, const int* __restrict__ batch,
    float* __restrict__ pooled) {
    int col = threadIdx.x & 127;
    int half = threadIdx.x >> 7;
    int row0 = blockIdx.x * 128;
    int rend = row0 + 128;
    if (rend > NA_N) rend = NA_N;
    float acc = 0.f;
    int cur_g = -1;
    for (int r = row0 + half; r < rend; r += 2) {
        int g = batch[r];
        if (g != cur_g) {
            if (cur_g >= 0) atomicAdd(&pooled[cur_g * DF + col], acc);
            cur_g = g;
            acc = 0.f;
        }
        acc += bf2f(xa[(size_t)r * DF + col]);
    }
    if (cur_g >= 0) atomicAdd(&pooled[cur_g * DF + col], acc);
}

__global__ void out_head_k(const float* __restrict__ pooled, const int* __restrict__ batch,
                           const float* __restrict__ Wout, const float* __restrict__ bout,
                           float* __restrict__ out) {
    int tid = threadIdx.x;
    if (tid >= NG_N * NC_N) return;
    int g = tid / NC_N, c = tid % NC_N;
    int lo = lb_search(batch, NA_N, g);
    int hi = lb_search(batch, NA_N, g + 1);
    int cnt = hi - lo;
    float inv = 1.0f / (float)(cnt > 0 ? cnt : 1);
    float s = 0.f;
    for (int k = 0; k < DF; k++) s += pooled[g * DF + k] * Wout[k * NC_N + c];
    out[tid] = s * inv + bout[c];
}

// ---------------- launcher ----------------

extern "C" void kernel_launch(void* const* d_in, const int* in_sizes, int n_in,
                              void* d_out, int out_size, void* d_ws, size_t ws_size,
                              hipStream_t stream) {
    const float* x_a = (const float*)d_in[0];
    const float* x_b = (const float*)d_in[1];
    const int* ei_aa = (const int*)d_in[2];
    const int* ei_ab = (const int*)d_in[3];
    const int* ei_ba = (const int*)d_in[4];
    const int* batch = (const int*)d_in[5];
    const float *Wn0_aa = (const float*)d_in[6],  *bn0_aa = (const float*)d_in[7],  *Wr0_aa = (const float*)d_in[8];
    const float *Wn0_ab = (const float*)d_in[9],  *bn0_ab = (const float*)d_in[10], *Wr0_ab = (const float*)d_in[11];
    const float *Wn0_ba = (const float*)d_in[12], *bn0_ba = (const float*)d_in[13], *Wr0_ba = (const float*)d_in[14];
    const float *Wn1_aa = (const float*)d_in[15], *bn1_aa = (const float*)d_in[16], *Wr1_aa = (const float*)d_in[17];
    // d_in[18..20] unused (layer-2 out_b never consumed)
    const float *Wn1_ba = (const float*)d_in[21], *bn1_ba = (const float*)d_in[22], *Wr1_ba = (const float*)d_in[23];
    const float *W_out = (const float*)d_in[24], *b_out = (const float*)d_in[25];
    float* out = (float*)d_out;

    char* w = (char*)d_ws;
    size_t off = 0;
    auto alloc = [&](size_t b) -> char* {
        char* p = w + off;
        off += (b + 255) & ~(size_t)255;
        return p;
    };

    // CSR outputs (persist across both layers)
    int* offs_aa = (int*)alloc((NA_N + 1) * 4);
    int* ss_aa   = (int*)alloc((size_t)NE * 4);
    int* offs_ba = (int*)alloc((NA_N + 1) * 4);
    int* ss_ba   = (int*)alloc((size_t)NE * 4);
    int* offs_ab = (int*)alloc((NB_N + 1) * 4);
    int* ss_ab   = (int*)alloc((size_t)NE * 4);
    // shared sort scratch
    int* bcnt  = (int*)alloc(NBUK * 4);
    int* bbase = (int*)alloc((NBUK + 1) * 4);
    int* bcur  = (int*)alloc(NBUK * 4);
    unsigned* ebuf = (unsigned*)alloc((size_t)NE * 4);

    unsigned short* xa_bf   = (unsigned short*)alloc((size_t)NA_N * DF * 2);
    unsigned short* xb_bf   = (unsigned short*)alloc((size_t)NB_N * DF * 2);
    unsigned short* mean_aa = (unsigned short*)alloc((size_t)NA_N * DF * 2);
    unsigned short* mean_ba = (unsigned short*)alloc((size_t)NA_N * DF * 2);
    unsigned short* mean_ab = (unsigned short*)alloc((size_t)NB_N * DF * 2);
    unsigned short* xa1 = (unsigned short*)alloc((size_t)NA_N * DF * 2);
    unsigned short* xb1 = (unsigned short*)alloc((size_t)NB_N * DF * 2);
    unsigned short* xa2 = mean_ab;  // alias: mean_ab dead once layer-0 dst-b GEMM ran
    unsigned short* Wf[8];
    for (int i = 0; i < 8; i++) Wf[i] = (unsigned short*)alloc((size_t)DF * DF * 2);
    float* pooled = (float*)alloc(NG_N * DF * 4);

    const int BINBLK = (NE + CHB - 1) / CHB;   // 245

    auto build_csr = [&](const int* ei, int ndst, int* offs, int* ss) {
        const int* srcp = ei;
        const int* dstp = ei + NE;
        hipMemsetAsync(bcnt, 0, NBUK * sizeof(int), stream);
        bucket_hist_k<<<BINBLK, 256, 0, stream>>>(dstp, bcnt);
        bucket_scan_k<<<1, 512, 0, stream>>>(bcnt, bbase, bcur);
        bucket_bin_k<<<BINBLK, 256, 0, stream>>>(srcp, dstp, bcur, ebuf);
        bucket_sort_k<<<NBUK, 256, 0, stream>>>(ebuf, bbase, offs, ss, ndst);
    };

    build_csr(ei_aa, NA_N, offs_aa, ss_aa);
    build_csr(ei_ba, NA_N, offs_ba, ss_ba);
    build_csr(ei_ab, NB_N, offs_ab, ss_ab);

    // feature conversion fp32 -> bf16
    const int CN4 = NA_N * DF / 4;
    convert_bf_k<<<(CN4 + 255) / 256, 256, 0, stream>>>(x_a, xa_bf, CN4);
    convert_bf_k<<<(CN4 + 255) / 256, 256, 0, stream>>>(x_b, xb_bf, CN4);

    // weights -> fragment order (Wr pairs summed here)
    prearrange_w_k<<<64, 256, 0, stream>>>(Wn0_aa, nullptr, Wf[0]);
    prearrange_w_k<<<64, 256, 0, stream>>>(Wn0_ba, nullptr, Wf[1]);
    prearrange_w_k<<<64, 256, 0, stream>>>(Wr0_aa, Wr0_ba, Wf[2]);
    prearrange_w_k<<<64, 256, 0, stream>>>(Wn0_ab, nullptr, Wf[3]);
    prearrange_w_k<<<64, 256, 0, stream>>>(Wr0_ab, nullptr, Wf[4]);
    prearrange_w_k<<<64, 256, 0, stream>>>(Wn1_aa, nullptr, Wf[5]);
    prearrange_w_k<<<64, 256, 0, stream>>>(Wn1_ba, nullptr, Wf[6]);
    prearrange_w_k<<<64, 256, 0, stream>>>(Wr1_aa, Wr1_ba, Wf[7]);

    const int AGG_BLK_A = (NA_N * 64 + 255) / 256;
    const int AGG_BLK_B = (NB_N * 64 + 255) / 256;
    const int GEMM_BLK_A = (NA_N + 127) / 128;
    const int GEMM_BLK_B = (NB_N + 127) / 128;

    // ---- layer 0 ----
    aggregate_bf_k<<<AGG_BLK_A, 256, 0, stream>>>(xa_bf, offs_aa, ss_aa, mean_aa, NA_N);
    aggregate_bf_k<<<AGG_BLK_A, 256, 0, stream>>>(xb_bf, offs_ba, ss_ba, mean_ba, NA_N);
    aggregate_bf_k<<<AGG_BLK_B, 256, 0, stream>>>(xa_bf, offs_ab, ss_ab, mean_ab, NB_N);
    gemm_mfma_k<<<GEMM_BLK_A, 256, 0, stream>>>(
        mean_aa, Wf[0], mean_ba, Wf[1], xa_bf, Wf[2],
        bn0_aa, bn0_ba, 3, NA_N, xa1);
    gemm_mfma_k<<<GEMM_BLK_B, 256, 0, stream>>>(
        mean_ab, Wf[3], xb_bf, Wf[4], nullptr, nullptr,
        bn0_ab, nullptr, 2, NB_N, xb1);

    // ---- layer 1 (out_b unused downstream -> skipped) ----
    aggregate_bf_k<<<AGG_BLK_A, 256, 0, stream>>>(xa1, offs_aa, ss_aa, mean_aa, NA_N);
    aggregate_bf_k<<<AGG_BLK_A, 256, 0, stream>>>(xb1, offs_ba, ss_ba, mean_ba, NA_N);
    gemm_mfma_k<<<GEMM_BLK_A, 256, 0, stream>>>(
        mean_aa, Wf[5], mean_ba, Wf[6], xa1, Wf[7],
        bn1_aa, bn1_ba, 3, NA_N, xa2);

    // ---- pool + head ----
    hipMemsetAsync(pooled, 0, (size_t)NG_N * DF * sizeof(float), stream);
    pool_partial_k<<<(NA_N + 127) / 128, 256, 0, stream>>>(xa2, batch, pooled);
    out_head_k<<<1, 640, 0, stream>>>(pooled, batch, W_out, b_out, out);
}

// Round 5
// 515.748 us; speedup vs baseline: 2.4753x; 1.2275x over previous
//
#include <hip/hip_runtime.h>

#define NA_N 50000
#define NB_N 50000
#define NE   1000000
#define DF   128
#define NG_N 64
#define NC_N 10

// bucketed counting sort params
#define BSHIFT 7
#define BNODES 128                       // nodes per bucket
#define NBUK   391                       // ceil(50000/128)
#define CHB    4096                      // edges per binning block
#define NIT    (CHB / 256)               // 16 edges per thread
#define BINBLK ((NE + CHB - 1) / CHB)    // 245
#define AGGBLK ((NA_N * 64) / 256)       // 12500 blocks per aggregation job

typedef __attribute__((ext_vector_type(8))) short short8;
typedef __attribute__((ext_vector_type(8))) unsigned short ushort8;
typedef __attribute__((ext_vector_type(4))) float float4v;

__device__ __forceinline__ unsigned short f2bf(float f) {
    unsigned u = __float_as_uint(f);
    unsigned r = (u + 0x7fff + ((u >> 16) & 1)) >> 16;   // RNE
    return (unsigned short)r;
}
__device__ __forceinline__ float bf2f(unsigned short b) {
    return __uint_as_float(((unsigned)b) << 16);
}

// ---------------- fp32 -> bf16 convert (both feature arrays, one launch) ----------------

__global__ void convert_bf2_k(const float* __restrict__ xa, const float* __restrict__ xb,
                              unsigned short* __restrict__ ya, unsigned short* __restrict__ yb,
                              int n4a, int n4tot) {
    int i = blockIdx.x * 256 + threadIdx.x;
    if (i >= n4tot) return;
    const float* x = (i < n4a) ? xa : xb;
    unsigned short* y = (i < n4a) ? ya : yb;
    int j = (i < n4a) ? i : i - n4a;
    float4 v = ((const float4*)x)[j];
    ushort4 o;
    o.x = f2bf(v.x); o.y = f2bf(v.y); o.z = f2bf(v.z); o.w = f2bf(v.w);
    ((ushort4*)y)[j] = o;
}

// ---------------- weights -> B-fragment order, all 8 in one launch ----------------

struct WJobs {
    const float* a[8];
    const float* b[8];
    unsigned short* d[8];
};

__global__ void prearrange_w8_k(WJobs J) {
    int which = blockIdx.x >> 6;               // 64 blocks per job
    int t = (blockIdx.x & 63) * 256 + threadIdx.x;   // 0..16383
    int j = t & 7, lane = (t >> 3) & 63, k0i = (t >> 9) & 3, n0 = t >> 11;
    int k = k0i * 32 + (lane >> 4) * 8 + j;
    int n = n0 * 16 + (lane & 15);
    float v = J.a[which][k * DF + n];
    if (J.b[which]) v += J.b[which][k * DF + n];
    J.d[which][t] = f2bf(v);
}

// ---------------- CSR build: 3 edge types batched per pass ----------------

struct CsrJobs {
    const int* src[3];
    const int* dst[3];
    int* offs[3];
    int* ss[3];
    unsigned* ebuf[3];
};

__global__ __launch_bounds__(256) void bucket_hist3_k(CsrJobs J, int* __restrict__ bcnt3) {
    int which = blockIdx.x / BINBLK;
    int blk = blockIdx.x % BINBLK;
    const int* dst = J.dst[which];
    int* bcnt = bcnt3 + which * NBUK;
    __shared__ int h[NBUK];
    for (int i = threadIdx.x; i < NBUK; i += 256) h[i] = 0;
    __syncthreads();
    int base = blk * CHB;
#pragma unroll
    for (int it = 0; it < NIT; it++) {
        int i = base + it * 256 + threadIdx.x;
        if (i < NE) atomicAdd(&h[dst[i] >> BSHIFT], 1);
    }
    __syncthreads();
    for (int i = threadIdx.x; i < NBUK; i += 256)
        if (h[i]) atomicAdd(&bcnt[i], h[i]);
}

__global__ void bucket_scan3_k(const int* __restrict__ bcnt3,
                               int* __restrict__ bbase3, int* __restrict__ bcur3) {
    __shared__ int s[512];
    int which = blockIdx.x;
    const int* bcnt = bcnt3 + which * NBUK;
    int* bbase = bbase3 + which * (NBUK + 1);
    int* bcur = bcur3 + which * NBUK;
    int t = threadIdx.x;
    int v = (t < NBUK) ? bcnt[t] : 0;
    s[t] = v;
    __syncthreads();
    for (int d = 1; d < 512; d <<= 1) {
        int x = (t >= d) ? s[t - d] : 0;
        __syncthreads();
        if (t >= d) s[t] += x;
        __syncthreads();
    }
    if (t < NBUK) {
        int e = s[t] - v;
        bbase[t] = e;
        bcur[t] = e;
    }
    if (t == 0) bbase[NBUK] = NE;
}

__global__ __launch_bounds__(256) void bucket_bin3_k(CsrJobs J, int* __restrict__ bcur3) {
    int which = blockIdx.x / BINBLK;
    int blk = blockIdx.x % BINBLK;
    const int* src = J.src[which];
    const int* dst = J.dst[which];
    int* bcur = bcur3 + which * NBUK;
    unsigned* ebuf = J.ebuf[which];
    __shared__ int cnt[NBUK];
    __shared__ int chunk[NBUK];
    for (int i = threadIdx.x; i < NBUK; i += 256) cnt[i] = 0;
    __syncthreads();
    int base = blk * CHB;
    int bk[NIT], rk[NIT];
    unsigned sv[NIT];
#pragma unroll
    for (int it = 0; it < NIT; it++) {
        int i = base + it * 256 + threadIdx.x;
        if (i < NE) {
            int d = dst[i];
            int b = d >> BSHIFT;
            bk[it] = b;
            rk[it] = atomicAdd(&cnt[b], 1);
            sv[it] = (unsigned)src[i] | ((unsigned)(d & (BNODES - 1)) << 24);
        } else {
            bk[it] = -1;
        }
    }
    __syncthreads();
    for (int i = threadIdx.x; i < NBUK; i += 256)
        chunk[i] = cnt[i] ? atomicAdd(&bcur[i], cnt[i]) : 0;
    __syncthreads();
#pragma unroll
    for (int it = 0; it < NIT; it++)
        if (bk[it] >= 0) ebuf[chunk[bk[it]] + rk[it]] = sv[it];
}

__global__ __launch_bounds__(256) void bucket_sort3_k(CsrJobs J, const int* __restrict__ bbase3,
                                                      int ndst) {
    __shared__ int hist[BNODES];
    __shared__ int loffs[BNODES];
    int which = blockIdx.x / NBUK;
    int b = blockIdx.x % NBUK;
    const unsigned* ebuf = J.ebuf[which];
    const int* bbase = bbase3 + which * (NBUK + 1);
    int* offs = J.offs[which];
    int* ss = J.ss[which];
    int t = threadIdx.x;
    int ebase = bbase[b], ecnt = bbase[b + 1] - ebase;
    if (t < BNODES) hist[t] = 0;
    __syncthreads();
    for (int e = t; e < ecnt; e += 256)
        atomicAdd(&hist[ebuf[ebase + e] >> 24], 1);
    __syncthreads();
    if (t < BNODES) loffs[t] = hist[t];
    __syncthreads();
    for (int d = 1; d < BNODES; d <<= 1) {
        int x = 0;
        if (t < BNODES && t >= d) x = loffs[t - d];
        __syncthreads();
        if (t < BNODES && t >= d) loffs[t] += x;
        __syncthreads();
    }
    if (t < BNODES) {
        int ex = loffs[t] - hist[t];
        loffs[t] = ex;
        int gnode = b * BNODES + t;
        if (gnode < ndst) offs[gnode] = ebase + ex;
        hist[t] = 0;
    }
    if (b == 0 && t == 0) offs[ndst] = NE;
    __syncthreads();
    for (int e = t; e < ecnt; e += 256) {
        unsigned w = ebuf[ebase + e];
        int dl = w >> 24;
        int r = atomicAdd(&hist[dl], 1);
        ss[ebase + loffs[dl] + r] = (int)(w & 0xFFFFFF);
    }
}

// ---------------- segment mean, multi-job fused, unroll-2 gather ----------------
// 1 wave / dst node; lanes split 4 ways over edges, 16 lanes x 16B per row;
// 2 independent row loads in flight per lane (latency hiding).

struct AggJobs {
    const unsigned short* xs[3];
    const int* offs[3];
    const int* ss[3];
    unsigned short* mean[3];
};

__global__ __launch_bounds__(256) void aggregate_multi_k(AggJobs J) {
    int job = blockIdx.x / AGGBLK;
    int blk = blockIdx.x % AGGBLK;
    int node = (blk * 256 + threadIdx.x) >> 6;
    int lane = threadIdx.x & 63;
    const unsigned short* xs = J.xs[job];
    const int* offs = J.offs[job];
    const int* ss = J.ss[job];
    int o0 = offs[node], o1 = offs[node + 1];
    int sub = lane >> 4;
    int q = lane & 15;
    float acc[8] = {0.f, 0.f, 0.f, 0.f, 0.f, 0.f, 0.f, 0.f};
    int e = o0 + sub;
    for (; e + 4 < o1; e += 8) {
        int s0 = ss[e];
        int s1 = ss[e + 4];
        ushort8 v0 = *(const ushort8*)(xs + (size_t)s0 * DF + q * 8);
        ushort8 v1 = *(const ushort8*)(xs + (size_t)s1 * DF + q * 8);
#pragma unroll
        for (int j = 0; j < 8; j++) acc[j] += bf2f(v0[j]) + bf2f(v1[j]);
    }
    if (e < o1) {
        int s = ss[e];
        ushort8 v = *(const ushort8*)(xs + (size_t)s * DF + q * 8);
#pragma unroll
        for (int j = 0; j < 8; j++) acc[j] += bf2f(v[j]);
    }
#pragma unroll
    for (int j = 0; j < 8; j++) {
        acc[j] += __shfl_down(acc[j], 32, 64);
        acc[j] += __shfl_down(acc[j], 16, 64);
    }
    if (sub == 0) {
        int cnt = o1 - o0;
        float inv = 1.0f / (float)(cnt > 0 ? cnt : 1);
        ushort4 r0, r1;
        r0.x = f2bf(acc[0] * inv); r0.y = f2bf(acc[1] * inv);
        r0.z = f2bf(acc[2] * inv); r0.w = f2bf(acc[3] * inv);
        r1.x = f2bf(acc[4] * inv); r1.y = f2bf(acc[5] * inv);
        r1.z = f2bf(acc[6] * inv); r1.w = f2bf(acc[7] * inv);
        unsigned short* mean = J.mean[job];
        *(ushort4*)(mean + (size_t)node * DF + q * 8) = r0;
        *(ushort4*)(mean + (size_t)node * DF + q * 8 + 4) = r1;
    }
}

// ---------------- bf16 MFMA GEMM ----------------

__global__ __launch_bounds__(256) void gemm_mfma_k(
    const unsigned short* __restrict__ A0, const unsigned short* __restrict__ Wf0,
    const unsigned short* __restrict__ A1, const unsigned short* __restrict__ Wf1,
    const unsigned short* __restrict__ A2, const unsigned short* __restrict__ Wf2,
    const float* __restrict__ b0, const float* __restrict__ b1,
    int nmats, int nrows, unsigned short* __restrict__ out) {
    int lane = threadIdx.x & 63;
    int wv = threadIdx.x >> 6;
    int r0 = blockIdx.x * 128 + wv * 32;
    int m = lane & 15, quad = lane >> 4;
    int rowA = r0 + m;      if (rowA >= nrows) rowA = nrows - 1;
    int rowB = r0 + 16 + m; if (rowB >= nrows) rowB = nrows - 1;

    float4v acc0[8], acc1[8];
#pragma unroll
    for (int n0 = 0; n0 < 8; n0++) {
        acc0[n0] = (float4v){0.f, 0.f, 0.f, 0.f};
        acc1[n0] = (float4v){0.f, 0.f, 0.f, 0.f};
    }

    for (int mat = 0; mat < nmats; mat++) {
        const unsigned short* A  = (mat == 0) ? A0  : ((mat == 1) ? A1  : A2);
        const unsigned short* Wf = (mat == 0) ? Wf0 : ((mat == 1) ? Wf1 : Wf2);
#pragma unroll
        for (int k0i = 0; k0i < 4; k0i++) {
            short8 a0 = *(const short8*)(A + (size_t)rowA * DF + k0i * 32 + quad * 8);
            short8 a1 = *(const short8*)(A + (size_t)rowB * DF + k0i * 32 + quad * 8);
#pragma unroll
            for (int n0 = 0; n0 < 8; n0++) {
                short8 b = *(const short8*)(Wf + (((n0 * 4 + k0i) * 64 + lane) << 3));
                acc0[n0] = __builtin_amdgcn_mfma_f32_16x16x32_bf16(a0, b, acc0[n0], 0, 0, 0);
                acc1[n0] = __builtin_amdgcn_mfma_f32_16x16x32_bf16(a1, b, acc1[n0], 0, 0, 0);
            }
        }
    }

#pragma unroll
    for (int n0 = 0; n0 < 8; n0++) {
        int c = n0 * 16 + m;
        float bb = b0[c] + (b1 ? b1[c] : 0.f);
#pragma unroll
        for (int i = 0; i < 4; i++) {
            int r = r0 + quad * 4 + i;
            if (r < nrows) out[(size_t)r * DF + c] = f2bf(fmaxf(acc0[n0][i] + bb, 0.f));
            int r2 = r0 + 16 + quad * 4 + i;
            if (r2 < nrows) out[(size_t)r2 * DF + c] = f2bf(fmaxf(acc1[n0][i] + bb, 0.f));
        }
    }
}

// ---------------- pooling + head ----------------

__device__ __forceinline__ int lb_search(const int* a, int n, int v) {
    int lo = 0, hi = n;
    while (lo < hi) {
        int mm = (lo + hi) >> 1;
        if (a[mm] < v) lo = mm + 1; else hi = mm;
    }
    return lo;
}

__global__ __launch_bounds__(256) void pool_partial_k(
    const unsigned short* __restrict__ xa, const int* __restrict__ batch,
    float* __restrict__ pooled) {
    int col = threadIdx.x & 127;
    int half = threadIdx.x >> 7;
    int row0 = blockIdx.x * 128;
    int rend = row0 + 128;
    if (rend > NA_N) rend = NA_N;
    float acc = 0.f;
    int cur_g = -1;
    for (int r = row0 + half; r < rend; r += 2) {
        int g = batch[r];
        if (g != cur_g) {
            if (cur_g >= 0) atomicAdd(&pooled[cur_g * DF + col], acc);
            cur_g = g;
            acc = 0.f;
        }
        acc += bf2f(xa[(size_t)r * DF + col]);
    }
    if (cur_g >= 0) atomicAdd(&pooled[cur_g * DF + col], acc);
}

__global__ void out_head_k(const float* __restrict__ pooled, const int* __restrict__ batch,
                           const float* __restrict__ Wout, const float* __restrict__ bout,
                           float* __restrict__ out) {
    int tid = threadIdx.x;
    if (tid >= NG_N * NC_N) return;
    int g = tid / NC_N, c = tid % NC_N;
    int lo = lb_search(batch, NA_N, g);
    int hi = lb_search(batch, NA_N, g + 1);
    int cnt = hi - lo;
    float inv = 1.0f / (float)(cnt > 0 ? cnt : 1);
    float s = 0.f;
    for (int k = 0; k < DF; k++) s += pooled[g * DF + k] * Wout[k * NC_N + c];
    out[tid] = s * inv + bout[c];
}

// ---------------- launcher ----------------

extern "C" void kernel_launch(void* const* d_in, const int* in_sizes, int n_in,
                              void* d_out, int out_size, void* d_ws, size_t ws_size,
                              hipStream_t stream) {
    const float* x_a = (const float*)d_in[0];
    const float* x_b = (const float*)d_in[1];
    const int* ei_aa = (const int*)d_in[2];
    const int* ei_ab = (const int*)d_in[3];
    const int* ei_ba = (const int*)d_in[4];
    const int* batch = (const int*)d_in[5];
    const float *Wn0_aa = (const float*)d_in[6],  *bn0_aa = (const float*)d_in[7],  *Wr0_aa = (const float*)d_in[8];
    const float *Wn0_ab = (const float*)d_in[9],  *bn0_ab = (const float*)d_in[10], *Wr0_ab = (const float*)d_in[11];
    const float *Wn0_ba = (const float*)d_in[12], *bn0_ba = (const float*)d_in[13], *Wr0_ba = (const float*)d_in[14];
    const float *Wn1_aa = (const float*)d_in[15], *bn1_aa = (const float*)d_in[16], *Wr1_aa = (const float*)d_in[17];
    // d_in[18..20] unused (layer-2 out_b never consumed)
    const float *Wn1_ba = (const float*)d_in[21], *bn1_ba = (const float*)d_in[22], *Wr1_ba = (const float*)d_in[23];
    const float *W_out = (const float*)d_in[24], *b_out = (const float*)d_in[25];
    float* out = (float*)d_out;

    char* w = (char*)d_ws;
    size_t off = 0;
    auto alloc = [&](size_t b) -> char* {
        char* p = w + off;
        off += (b + 255) & ~(size_t)255;
        return p;
    };

    // CSR outputs (persist across both layers)
    int* offs_aa = (int*)alloc((NA_N + 1) * 4);
    int* ss_aa   = (int*)alloc((size_t)NE * 4);
    int* offs_ba = (int*)alloc((NA_N + 1) * 4);
    int* ss_ba   = (int*)alloc((size_t)NE * 4);
    int* offs_ab = (int*)alloc((NB_N + 1) * 4);
    int* ss_ab   = (int*)alloc((size_t)NE * 4);
    // sort scratch (per edge type now, for batched passes)
    int* bcnt3  = (int*)alloc(3 * NBUK * 4);
    int* bbase3 = (int*)alloc(3 * (NBUK + 1) * 4);
    int* bcur3  = (int*)alloc(3 * NBUK * 4);
    unsigned* ebuf0 = (unsigned*)alloc((size_t)NE * 4);
    unsigned* ebuf1 = (unsigned*)alloc((size_t)NE * 4);
    unsigned* ebuf2 = (unsigned*)alloc((size_t)NE * 4);

    unsigned short* xa_bf   = (unsigned short*)alloc((size_t)NA_N * DF * 2);
    unsigned short* xb_bf   = (unsigned short*)alloc((size_t)NB_N * DF * 2);
    unsigned short* mean_aa = (unsigned short*)alloc((size_t)NA_N * DF * 2);
    unsigned short* mean_ba = (unsigned short*)alloc((size_t)NA_N * DF * 2);
    unsigned short* mean_ab = (unsigned short*)alloc((size_t)NB_N * DF * 2);
    unsigned short* xa1 = (unsigned short*)alloc((size_t)NA_N * DF * 2);
    unsigned short* xb1 = (unsigned short*)alloc((size_t)NB_N * DF * 2);
    unsigned short* xa2 = mean_ab;  // alias: mean_ab dead once layer-0 dst-b GEMM ran
    unsigned short* Wf[8];
    for (int i = 0; i < 8; i++) Wf[i] = (unsigned short*)alloc((size_t)DF * DF * 2);
    float* pooled = (float*)alloc(NG_N * DF * 4);

    // ---- CSR build (3 edge types batched) ----
    CsrJobs CJ;
    CJ.src[0] = ei_aa;      CJ.dst[0] = ei_aa + NE;
    CJ.src[1] = ei_ba;      CJ.dst[1] = ei_ba + NE;
    CJ.src[2] = ei_ab;      CJ.dst[2] = ei_ab + NE;
    CJ.offs[0] = offs_aa;   CJ.ss[0] = ss_aa;   CJ.ebuf[0] = ebuf0;
    CJ.offs[1] = offs_ba;   CJ.ss[1] = ss_ba;   CJ.ebuf[1] = ebuf1;
    CJ.offs[2] = offs_ab;   CJ.ss[2] = ss_ab;   CJ.ebuf[2] = ebuf2;

    hipMemsetAsync(bcnt3, 0, 3 * NBUK * sizeof(int), stream);
    bucket_hist3_k<<<3 * BINBLK, 256, 0, stream>>>(CJ, bcnt3);
    bucket_scan3_k<<<3, 512, 0, stream>>>(bcnt3, bbase3, bcur3);
    bucket_bin3_k<<<3 * BINBLK, 256, 0, stream>>>(CJ, bcur3);
    bucket_sort3_k<<<3 * NBUK, 256, 0, stream>>>(CJ, bbase3, NA_N);

    // ---- feature conversion (both arrays, one launch) ----
    const int CN4A = NA_N * DF / 4, CN4T = (NA_N + NB_N) * DF / 4;
    convert_bf2_k<<<(CN4T + 255) / 256, 256, 0, stream>>>(x_a, x_b, xa_bf, xb_bf, CN4A, CN4T);

    // ---- weights -> fragment order, one launch (Wr pairs summed) ----
    WJobs WJ;
    WJ.a[0] = Wn0_aa; WJ.b[0] = nullptr; WJ.d[0] = Wf[0];
    WJ.a[1] = Wn0_ba; WJ.b[1] = nullptr; WJ.d[1] = Wf[1];
    WJ.a[2] = Wr0_aa; WJ.b[2] = Wr0_ba;  WJ.d[2] = Wf[2];
    WJ.a[3] = Wn0_ab; WJ.b[3] = nullptr; WJ.d[3] = Wf[3];
    WJ.a[4] = Wr0_ab; WJ.b[4] = nullptr; WJ.d[4] = Wf[4];
    WJ.a[5] = Wn1_aa; WJ.b[5] = nullptr; WJ.d[5] = Wf[5];
    WJ.a[6] = Wn1_ba; WJ.b[6] = nullptr; WJ.d[6] = Wf[6];
    WJ.a[7] = Wr1_aa; WJ.b[7] = Wr1_ba;  WJ.d[7] = Wf[7];
    prearrange_w8_k<<<8 * 64, 256, 0, stream>>>(WJ);

    const int GEMM_BLK = (NA_N + 127) / 128;

    // ---- layer 0: 3 aggregations fused ----
    AggJobs A0;
    A0.xs[0] = xa_bf; A0.offs[0] = offs_aa; A0.ss[0] = ss_aa; A0.mean[0] = mean_aa;
    A0.xs[1] = xb_bf; A0.offs[1] = offs_ba; A0.ss[1] = ss_ba; A0.mean[1] = mean_ba;
    A0.xs[2] = xa_bf; A0.offs[2] = offs_ab; A0.ss[2] = ss_ab; A0.mean[2] = mean_ab;
    aggregate_multi_k<<<3 * AGGBLK, 256, 0, stream>>>(A0);

    gemm_mfma_k<<<GEMM_BLK, 256, 0, stream>>>(
        mean_aa, Wf[0], mean_ba, Wf[1], xa_bf, Wf[2],
        bn0_aa, bn0_ba, 3, NA_N, xa1);
    gemm_mfma_k<<<GEMM_BLK, 256, 0, stream>>>(
        mean_ab, Wf[3], xb_bf, Wf[4], nullptr, nullptr,
        bn0_ab, nullptr, 2, NB_N, xb1);

    // ---- layer 1: 2 aggregations fused (out_b unused downstream -> skipped) ----
    AggJobs A1;
    A1.xs[0] = xa1; A1.offs[0] = offs_aa; A1.ss[0] = ss_aa; A1.mean[0] = mean_aa;
    A1.xs[1] = xb1; A1.offs[1] = offs_ba; A1.ss[1] = ss_ba; A1.mean[1] = mean_ba;
    A1.xs[2] = xa1; A1.offs[2] = offs_aa; A1.ss[2] = ss_aa; A1.mean[2] = mean_aa; // unused slot
    aggregate_multi_k<<<2 * AGGBLK, 256, 0, stream>>>(A1);

    gemm_mfma_k<<<GEMM_BLK, 256, 0, stream>>>(
        mean_aa, Wf[5], mean_ba, Wf[6], xa1, Wf[7],
        bn1_aa, bn1_ba, 3, NA_N, xa2);

    // ---- pool + head ----
    hipMemsetAsync(pooled, 0, (size_t)NG_N * DF * sizeof(float), stream);
    pool_partial_k<<<(NA_N + 127) / 128, 256, 0, stream>>>(xa2, batch, pooled);
    out_head_k<<<1, 640, 0, stream>>>(pooled, batch, W_out, b_out, out);
}

// Round 6
// 465.470 us; speedup vs baseline: 2.7427x; 1.1080x over previous
//
#include <hip/hip_runtime.h>

#define NA_N 50000
#define NB_N 50000
#define NE   1000000
#define DF   128
#define NG_N 64
#define NC_N 10

// bucketed counting sort params
#define BSHIFT 7
#define BNODES 128
#define NBUK   391
#define CHB    4096
#define NIT    (CHB / 256)
#define BINBLK ((NE + CHB - 1) / CHB)    // 245
#define AGGBLK ((NA_N * 64) / 256)       // 12500 blocks per aggregation job

#define CN4A (NA_N * DF / 4)
#define CN4T ((NA_N + NB_N) * DF / 4)
#define WELEMS (8 * 16384)
#define PZ4 (NG_N * DF / 4)

typedef __attribute__((ext_vector_type(8))) short short8;
typedef __attribute__((ext_vector_type(4))) float float4v;

__device__ __forceinline__ unsigned short f2bf(float f) {
    unsigned u = __float_as_uint(f);
    unsigned r = (u + 0x7fff + ((u >> 16) & 1)) >> 16;   // RNE
    return (unsigned short)r;
}
__device__ __forceinline__ float bf_lo(unsigned d) { return __uint_as_float(d << 16); }
__device__ __forceinline__ float bf_hi(unsigned d) { return __uint_as_float(d & 0xffff0000u); }
__device__ __forceinline__ unsigned packbf(float lo, float hi) {
    return (unsigned)f2bf(lo) | ((unsigned)f2bf(hi) << 16);
}

// ---------------- fused prep: feature convert + weight prearrange + pooled zero ----------------

struct WJobs {
    const float* a[8];
    const float* b[8];
    unsigned short* d[8];
};

__global__ void prep_k(const float* __restrict__ xa, const float* __restrict__ xb,
                       unsigned short* __restrict__ ya, unsigned short* __restrict__ yb,
                       WJobs WJ, float* __restrict__ pooled) {
    int i = blockIdx.x * 256 + threadIdx.x;
    if (i < CN4T) {
        const float* x = (i < CN4A) ? xa : xb;
        unsigned short* y = (i < CN4A) ? ya : yb;
        int j = (i < CN4A) ? i : i - CN4A;
        float4 v = ((const float4*)x)[j];
        uint2 o;
        o.x = packbf(v.x, v.y);
        o.y = packbf(v.z, v.w);
        ((uint2*)y)[j] = o;
    } else if (i < CN4T + WELEMS) {
        int t = i - CN4T;
        int which = t >> 14;
        t &= 16383;
        int j = t & 7, lane = (t >> 3) & 63, k0i = (t >> 9) & 3, n0 = t >> 11;
        int k = k0i * 32 + (lane >> 4) * 8 + j;
        int n = n0 * 16 + (lane & 15);
        float v = WJ.a[which][k * DF + n];
        if (WJ.b[which]) v += WJ.b[which][k * DF + n];
        WJ.d[which][t] = f2bf(v);
    } else if (i < CN4T + WELEMS + PZ4) {
        int t = i - CN4T - WELEMS;
        ((float4*)pooled)[t] = (float4){0.f, 0.f, 0.f, 0.f};
    }
}

// ---------------- CSR build: 3 edge types batched per pass ----------------

struct CsrJobs {
    const int* src[3];
    const int* dst[3];
    int* offs[3];
    int* ss[3];
    unsigned* ebuf[3];
};

__global__ __launch_bounds__(256) void bucket_hist3_k(CsrJobs J, int* __restrict__ bcnt3) {
    int which = blockIdx.x / BINBLK;
    int blk = blockIdx.x % BINBLK;
    const int* dst = J.dst[which];
    int* bcnt = bcnt3 + which * NBUK;
    __shared__ int h[NBUK];
    for (int i = threadIdx.x; i < NBUK; i += 256) h[i] = 0;
    __syncthreads();
    int base = blk * CHB;
#pragma unroll
    for (int it = 0; it < NIT; it++) {
        int i = base + it * 256 + threadIdx.x;
        if (i < NE) atomicAdd(&h[dst[i] >> BSHIFT], 1);
    }
    __syncthreads();
    for (int i = threadIdx.x; i < NBUK; i += 256)
        if (h[i]) atomicAdd(&bcnt[i], h[i]);
}

__global__ void bucket_scan3_k(const int* __restrict__ bcnt3,
                               int* __restrict__ bbase3, int* __restrict__ bcur3) {
    __shared__ int s[512];
    int which = blockIdx.x;
    const int* bcnt = bcnt3 + which * NBUK;
    int* bbase = bbase3 + which * (NBUK + 1);
    int* bcur = bcur3 + which * NBUK;
    int t = threadIdx.x;
    int v = (t < NBUK) ? bcnt[t] : 0;
    s[t] = v;
    __syncthreads();
    for (int d = 1; d < 512; d <<= 1) {
        int x = (t >= d) ? s[t - d] : 0;
        __syncthreads();
        if (t >= d) s[t] += x;
        __syncthreads();
    }
    if (t < NBUK) {
        int e = s[t] - v;
        bbase[t] = e;
        bcur[t] = e;
    }
    if (t == 0) bbase[NBUK] = NE;
}

__global__ __launch_bounds__(256) void bucket_bin3_k(CsrJobs J, int* __restrict__ bcur3) {
    int which = blockIdx.x / BINBLK;
    int blk = blockIdx.x % BINBLK;
    const int* src = J.src[which];
    const int* dst = J.dst[which];
    int* bcur = bcur3 + which * NBUK;
    unsigned* ebuf = J.ebuf[which];
    __shared__ int cnt[NBUK];
    __shared__ int chunk[NBUK];
    for (int i = threadIdx.x; i < NBUK; i += 256) cnt[i] = 0;
    __syncthreads();
    int base = blk * CHB;
    int bk[NIT], rk[NIT];
    unsigned sv[NIT];
#pragma unroll
    for (int it = 0; it < NIT; it++) {
        int i = base + it * 256 + threadIdx.x;
        if (i < NE) {
            int d = dst[i];
            int b = d >> BSHIFT;
            bk[it] = b;
            rk[it] = atomicAdd(&cnt[b], 1);
            sv[it] = (unsigned)src[i] | ((unsigned)(d & (BNODES - 1)) << 24);
        } else {
            bk[it] = -1;
        }
    }
    __syncthreads();
    for (int i = threadIdx.x; i < NBUK; i += 256)
        chunk[i] = cnt[i] ? atomicAdd(&bcur[i], cnt[i]) : 0;
    __syncthreads();
#pragma unroll
    for (int it = 0; it < NIT; it++)
        if (bk[it] >= 0) ebuf[chunk[bk[it]] + rk[it]] = sv[it];
}

__global__ __launch_bounds__(256) void bucket_sort3_k(CsrJobs J, const int* __restrict__ bbase3,
                                                      int ndst) {
    __shared__ int hist[BNODES];
    __shared__ int loffs[BNODES];
    int which = blockIdx.x / NBUK;
    int b = blockIdx.x % NBUK;
    const unsigned* ebuf = J.ebuf[which];
    const int* bbase = bbase3 + which * (NBUK + 1);
    int* offs = J.offs[which];
    int* ss = J.ss[which];
    int t = threadIdx.x;
    int ebase = bbase[b], ecnt = bbase[b + 1] - ebase;
    if (t < BNODES) hist[t] = 0;
    __syncthreads();
    for (int e = t; e < ecnt; e += 256)
        atomicAdd(&hist[ebuf[ebase + e] >> 24], 1);
    __syncthreads();
    if (t < BNODES) loffs[t] = hist[t];
    __syncthreads();
    for (int d = 1; d < BNODES; d <<= 1) {
        int x = 0;
        if (t < BNODES && t >= d) x = loffs[t - d];
        __syncthreads();
        if (t < BNODES && t >= d) loffs[t] += x;
        __syncthreads();
    }
    if (t < BNODES) {
        int ex = loffs[t] - hist[t];
        loffs[t] = ex;
        int gnode = b * BNODES + t;
        if (gnode < ndst) offs[gnode] = ebase + ex;
        hist[t] = 0;
    }
    if (b == 0 && t == 0) offs[ndst] = NE;
    __syncthreads();
    for (int e = t; e < ecnt; e += 256) {
        unsigned w = ebuf[ebase + e];
        int dl = w >> 24;
        int r = atomicAdd(&hist[dl], 1);
        ss[ebase + loffs[dl] + r] = (int)(w & 0xFFFFFF);
    }
}

// ---------------- segment mean, multi-job, packed bf16 accumulate ----------------
// 1 wave / dst node; 4 edges in parallel (16 lanes x 16B each), unroll 2.
// Per dword: lo = d<<16, hi = d&0xffff0000 (1 inst/value), float2 accumulate.

struct AggJobs {
    const unsigned short* xs[3];
    const int* offs[3];
    const int* ss[3];
    unsigned short* mean[3];
};

__global__ __launch_bounds__(256) void aggregate_multi_k(AggJobs J) {
    int job = blockIdx.x / AGGBLK;
    int blk = blockIdx.x % AGGBLK;
    int node = (blk * 256 + threadIdx.x) >> 6;
    int lane = threadIdx.x & 63;
    const unsigned* xs = (const unsigned*)J.xs[job];   // 64 dwords per row
    const int* offs = J.offs[job];
    const int* ss = J.ss[job];
    int o0 = offs[node], o1 = offs[node + 1];
    int sub = lane >> 4;
    int q4 = (lane & 15) * 4;                          // dword offset in row
    float2 acc[4];
#pragma unroll
    for (int k = 0; k < 4; k++) acc[k] = (float2){0.f, 0.f};

    int e = o0 + sub;
    for (; e + 4 < o1; e += 8) {
        int s0 = ss[e], s1 = ss[e + 4];
        uint4 u0 = *(const uint4*)(xs + (size_t)s0 * 64 + q4);
        uint4 u1 = *(const uint4*)(xs + (size_t)s1 * 64 + q4);
        acc[0].x += bf_lo(u0.x); acc[0].y += bf_hi(u0.x);
        acc[1].x += bf_lo(u0.y); acc[1].y += bf_hi(u0.y);
        acc[2].x += bf_lo(u0.z); acc[2].y += bf_hi(u0.z);
        acc[3].x += bf_lo(u0.w); acc[3].y += bf_hi(u0.w);
        acc[0].x += bf_lo(u1.x); acc[0].y += bf_hi(u1.x);
        acc[1].x += bf_lo(u1.y); acc[1].y += bf_hi(u1.y);
        acc[2].x += bf_lo(u1.z); acc[2].y += bf_hi(u1.z);
        acc[3].x += bf_lo(u1.w); acc[3].y += bf_hi(u1.w);
    }
    if (e < o1) {
        int s = ss[e];
        uint4 u = *(const uint4*)(xs + (size_t)s * 64 + q4);
        acc[0].x += bf_lo(u.x); acc[0].y += bf_hi(u.x);
        acc[1].x += bf_lo(u.y); acc[1].y += bf_hi(u.y);
        acc[2].x += bf_lo(u.z); acc[2].y += bf_hi(u.z);
        acc[3].x += bf_lo(u.w); acc[3].y += bf_hi(u.w);
    }
#pragma unroll
    for (int k = 0; k < 4; k++) {
        acc[k].x += __shfl_down(acc[k].x, 32, 64);
        acc[k].y += __shfl_down(acc[k].y, 32, 64);
        acc[k].x += __shfl_down(acc[k].x, 16, 64);
        acc[k].y += __shfl_down(acc[k].y, 16, 64);
    }
    if (sub == 0) {
        int cnt = o1 - o0;
        float inv = 1.0f / (float)(cnt > 0 ? cnt : 1);
        uint4 o;
        o.x = packbf(acc[0].x * inv, acc[0].y * inv);
        o.y = packbf(acc[1].x * inv, acc[1].y * inv);
        o.z = packbf(acc[2].x * inv, acc[2].y * inv);
        o.w = packbf(acc[3].x * inv, acc[3].y * inv);
        *(uint4*)((unsigned*)J.mean[job] + (size_t)node * 64 + q4) = o;
    }
}

// ---------------- bf16 MFMA GEMM, up to 2 jobs per launch ----------------

struct GemmJobs {
    const unsigned short* A[2][3];
    const unsigned short* Wf[2][3];
    const float* b0[2];
    const float* b1[2];
    unsigned short* outp[2];
    int nmats[2];
};

#define GEMM_BLK ((NA_N + 127) / 128)    // 391 (NA_N == NB_N)

__global__ __launch_bounds__(256) void gemm_mfma_multi_k(GemmJobs J) {
    int job = blockIdx.x / GEMM_BLK;
    int blk = blockIdx.x % GEMM_BLK;
    const int nrows = NA_N;
    int lane = threadIdx.x & 63;
    int wv = threadIdx.x >> 6;
    int r0 = blk * 128 + wv * 32;
    int m = lane & 15, quad = lane >> 4;
    int rowA = r0 + m;      if (rowA >= nrows) rowA = nrows - 1;
    int rowB = r0 + 16 + m; if (rowB >= nrows) rowB = nrows - 1;
    int nmats = J.nmats[job];

    float4v acc0[8], acc1[8];
#pragma unroll
    for (int n0 = 0; n0 < 8; n0++) {
        acc0[n0] = (float4v){0.f, 0.f, 0.f, 0.f};
        acc1[n0] = (float4v){0.f, 0.f, 0.f, 0.f};
    }

    for (int mat = 0; mat < nmats; mat++) {
        const unsigned short* A  = J.A[job][mat];
        const unsigned short* Wf = J.Wf[job][mat];
#pragma unroll
        for (int k0i = 0; k0i < 4; k0i++) {
            short8 a0 = *(const short8*)(A + (size_t)rowA * DF + k0i * 32 + quad * 8);
            short8 a1 = *(const short8*)(A + (size_t)rowB * DF + k0i * 32 + quad * 8);
#pragma unroll
            for (int n0 = 0; n0 < 8; n0++) {
                short8 b = *(const short8*)(Wf + (((n0 * 4 + k0i) * 64 + lane) << 3));
                acc0[n0] = __builtin_amdgcn_mfma_f32_16x16x32_bf16(a0, b, acc0[n0], 0, 0, 0);
                acc1[n0] = __builtin_amdgcn_mfma_f32_16x16x32_bf16(a1, b, acc1[n0], 0, 0, 0);
            }
        }
    }

    const float* b0 = J.b0[job];
    const float* b1 = J.b1[job];
    unsigned short* out = J.outp[job];
#pragma unroll
    for (int n0 = 0; n0 < 8; n0++) {
        int c = n0 * 16 + m;
        float bb = b0[c] + (b1 ? b1[c] : 0.f);
#pragma unroll
        for (int i = 0; i < 4; i++) {
            int r = r0 + quad * 4 + i;
            if (r < nrows) out[(size_t)r * DF + c] = f2bf(fmaxf(acc0[n0][i] + bb, 0.f));
            int r2 = r0 + 16 + quad * 4 + i;
            if (r2 < nrows) out[(size_t)r2 * DF + c] = f2bf(fmaxf(acc1[n0][i] + bb, 0.f));
        }
    }
}

// ---------------- pooling + head ----------------

__device__ __forceinline__ int lb_search(const int* a, int n, int v) {
    int lo = 0, hi = n;
    while (lo < hi) {
        int mm = (lo + hi) >> 1;
        if (a[mm] < v) lo = mm + 1; else hi = mm;
    }
    return lo;
}

// 64 lanes x 4B (2 cols) per row, 4 row-ways per block of 128 rows
__global__ __launch_bounds__(256) void pool_partial_k(
    const unsigned short* __restrict__ xa, const int* __restrict__ batch,
    float* __restrict__ pooled) {
    int c2 = threadIdx.x & 63;              // dword (2 cols)
    int way = threadIdx.x >> 6;             // 0..3
    int row0 = blockIdx.x * 128;
    int rend = row0 + 128;
    if (rend > NA_N) rend = NA_N;
    const unsigned* x = (const unsigned*)xa;
    float2 acc = {0.f, 0.f};
    int cur_g = -1;
    for (int r = row0 + way; r < rend; r += 4) {
        int g = batch[r];
        if (g != cur_g) {
            if (cur_g >= 0) {
                atomicAdd(&pooled[cur_g * DF + c2 * 2], acc.x);
                atomicAdd(&pooled[cur_g * DF + c2 * 2 + 1], acc.y);
            }
            cur_g = g;
            acc = (float2){0.f, 0.f};
        }
        unsigned d = x[(size_t)r * 64 + c2];
        acc.x += bf_lo(d);
        acc.y += bf_hi(d);
    }
    if (cur_g >= 0) {
        atomicAdd(&pooled[cur_g * DF + c2 * 2], acc.x);
        atomicAdd(&pooled[cur_g * DF + c2 * 2 + 1], acc.y);
    }
}

__global__ void out_head_k(const float* __restrict__ pooled, const int* __restrict__ batch,
                           const float* __restrict__ Wout, const float* __restrict__ bout,
                           float* __restrict__ out) {
    int tid = threadIdx.x;
    if (tid >= NG_N * NC_N) return;
    int g = tid / NC_N, c = tid % NC_N;
    int lo = lb_search(batch, NA_N, g);
    int hi = lb_search(batch, NA_N, g + 1);
    int cnt = hi - lo;
    float inv = 1.0f / (float)(cnt > 0 ? cnt : 1);
    float s = 0.f;
    for (int k = 0; k < DF; k++) s += pooled[g * DF + k] * Wout[k * NC_N + c];
    out[tid] = s * inv + bout[c];
}

// ---------------- launcher ----------------

extern "C" void kernel_launch(void* const* d_in, const int* in_sizes, int n_in,
                              void* d_out, int out_size, void* d_ws, size_t ws_size,
                              hipStream_t stream) {
    const float* x_a = (const float*)d_in[0];
    const float* x_b = (const float*)d_in[1];
    const int* ei_aa = (const int*)d_in[2];
    const int* ei_ab = (const int*)d_in[3];
    const int* ei_ba = (const int*)d_in[4];
    const int* batch = (const int*)d_in[5];
    const float *Wn0_aa = (const float*)d_in[6],  *bn0_aa = (const float*)d_in[7],  *Wr0_aa = (const float*)d_in[8];
    const float *Wn0_ab = (const float*)d_in[9],  *bn0_ab = (const float*)d_in[10], *Wr0_ab = (const float*)d_in[11];
    const float *Wn0_ba = (const float*)d_in[12], *bn0_ba = (const float*)d_in[13], *Wr0_ba = (const float*)d_in[14];
    const float *Wn1_aa = (const float*)d_in[15], *bn1_aa = (const float*)d_in[16], *Wr1_aa = (const float*)d_in[17];
    // d_in[18..20] unused (layer-2 out_b never consumed)
    const float *Wn1_ba = (const float*)d_in[21], *bn1_ba = (const float*)d_in[22], *Wr1_ba = (const float*)d_in[23];
    const float *W_out = (const float*)d_in[24], *b_out = (const float*)d_in[25];
    float* out = (float*)d_out;

    char* w = (char*)d_ws;
    size_t off = 0;
    auto alloc = [&](size_t b) -> char* {
        char* p = w + off;
        off += (b + 255) & ~(size_t)255;
        return p;
    };

    int* offs_aa = (int*)alloc((NA_N + 1) * 4);
    int* ss_aa   = (int*)alloc((size_t)NE * 4);
    int* offs_ba = (int*)alloc((NA_N + 1) * 4);
    int* ss_ba   = (int*)alloc((size_t)NE * 4);
    int* offs_ab = (int*)alloc((NB_N + 1) * 4);
    int* ss_ab   = (int*)alloc((size_t)NE * 4);
    int* bcnt3  = (int*)alloc(3 * NBUK * 4);
    int* bbase3 = (int*)alloc(3 * (NBUK + 1) * 4);
    int* bcur3  = (int*)alloc(3 * NBUK * 4);
    unsigned* ebuf0 = (unsigned*)alloc((size_t)NE * 4);
    unsigned* ebuf1 = (unsigned*)alloc((size_t)NE * 4);
    unsigned* ebuf2 = (unsigned*)alloc((size_t)NE * 4);

    unsigned short* xa_bf   = (unsigned short*)alloc((size_t)NA_N * DF * 2);
    unsigned short* xb_bf   = (unsigned short*)alloc((size_t)NB_N * DF * 2);
    unsigned short* mean_aa = (unsigned short*)alloc((size_t)NA_N * DF * 2);
    unsigned short* mean_ba = (unsigned short*)alloc((size_t)NA_N * DF * 2);
    unsigned short* mean_ab = (unsigned short*)alloc((size_t)NB_N * DF * 2);
    unsigned short* xa1 = (unsigned short*)alloc((size_t)NA_N * DF * 2);
    unsigned short* xb1 = (unsigned short*)alloc((size_t)NB_N * DF * 2);
    unsigned short* xa2 = mean_ab;  // alias: mean_ab dead once layer-0 dst-b GEMM ran
    unsigned short* Wf[8];
    for (int i = 0; i < 8; i++) Wf[i] = (unsigned short*)alloc((size_t)DF * DF * 2);
    float* pooled = (float*)alloc(NG_N * DF * 4);

    // ---- CSR build (3 edge types batched) ----
    CsrJobs CJ;
    CJ.src[0] = ei_aa;      CJ.dst[0] = ei_aa + NE;
    CJ.src[1] = ei_ba;      CJ.dst[1] = ei_ba + NE;
    CJ.src[2] = ei_ab;      CJ.dst[2] = ei_ab + NE;
    CJ.offs[0] = offs_aa;   CJ.ss[0] = ss_aa;   CJ.ebuf[0] = ebuf0;
    CJ.offs[1] = offs_ba;   CJ.ss[1] = ss_ba;   CJ.ebuf[1] = ebuf1;
    CJ.offs[2] = offs_ab;   CJ.ss[2] = ss_ab;   CJ.ebuf[2] = ebuf2;

    hipMemsetAsync(bcnt3, 0, 3 * NBUK * sizeof(int), stream);
    bucket_hist3_k<<<3 * BINBLK, 256, 0, stream>>>(CJ, bcnt3);
    bucket_scan3_k<<<3, 512, 0, stream>>>(bcnt3, bbase3, bcur3);
    bucket_bin3_k<<<3 * BINBLK, 256, 0, stream>>>(CJ, bcur3);
    bucket_sort3_k<<<3 * NBUK, 256, 0, stream>>>(CJ, bbase3, NA_N);

    // ---- fused prep: converts + weight prearrange (Wr pairs summed) + pooled zero ----
    WJobs WJ;
    WJ.a[0] = Wn0_aa; WJ.b[0] = nullptr; WJ.d[0] = Wf[0];
    WJ.a[1] = Wn0_ba; WJ.b[1] = nullptr; WJ.d[1] = Wf[1];
    WJ.a[2] = Wr0_aa; WJ.b[2] = Wr0_ba;  WJ.d[2] = Wf[2];
    WJ.a[3] = Wn0_ab; WJ.b[3] = nullptr; WJ.d[3] = Wf[3];
    WJ.a[4] = Wr0_ab; WJ.b[4] = nullptr; WJ.d[4] = Wf[4];
    WJ.a[5] = Wn1_aa; WJ.b[5] = nullptr; WJ.d[5] = Wf[5];
    WJ.a[6] = Wn1_ba; WJ.b[6] = nullptr; WJ.d[6] = Wf[6];
    WJ.a[7] = Wr1_aa; WJ.b[7] = Wr1_ba;  WJ.d[7] = Wf[7];
    const int PREP_ITEMS = CN4T + WELEMS + PZ4;
    prep_k<<<(PREP_ITEMS + 255) / 256, 256, 0, stream>>>(x_a, x_b, xa_bf, xb_bf, WJ, pooled);

    // ---- layer 0: 3 aggregations fused ----
    AggJobs A0;
    A0.xs[0] = xa_bf; A0.offs[0] = offs_aa; A0.ss[0] = ss_aa; A0.mean[0] = mean_aa;
    A0.xs[1] = xb_bf; A0.offs[1] = offs_ba; A0.ss[1] = ss_ba; A0.mean[1] = mean_ba;
    A0.xs[2] = xa_bf; A0.offs[2] = offs_ab; A0.ss[2] = ss_ab; A0.mean[2] = mean_ab;
    aggregate_multi_k<<<3 * AGGBLK, 256, 0, stream>>>(A0);

    // ---- layer 0: both GEMMs in one launch ----
    GemmJobs G0;
    G0.A[0][0] = mean_aa; G0.Wf[0][0] = Wf[0];
    G0.A[0][1] = mean_ba; G0.Wf[0][1] = Wf[1];
    G0.A[0][2] = xa_bf;   G0.Wf[0][2] = Wf[2];
    G0.b0[0] = bn0_aa; G0.b1[0] = bn0_ba; G0.outp[0] = xa1; G0.nmats[0] = 3;
    G0.A[1][0] = mean_ab; G0.Wf[1][0] = Wf[3];
    G0.A[1][1] = xb_bf;   G0.Wf[1][1] = Wf[4];
    G0.A[1][2] = nullptr; G0.Wf[1][2] = nullptr;
    G0.b0[1] = bn0_ab; G0.b1[1] = nullptr; G0.outp[1] = xb1; G0.nmats[1] = 2;
    gemm_mfma_multi_k<<<2 * GEMM_BLK, 256, 0, stream>>>(G0);

    // ---- layer 1: 2 aggregations fused (out_b unused downstream -> skipped) ----
    AggJobs A1;
    A1.xs[0] = xa1; A1.offs[0] = offs_aa; A1.ss[0] = ss_aa; A1.mean[0] = mean_aa;
    A1.xs[1] = xb1; A1.offs[1] = offs_ba; A1.ss[1] = ss_ba; A1.mean[1] = mean_ba;
    A1.xs[2] = xa1; A1.offs[2] = offs_aa; A1.ss[2] = ss_aa; A1.mean[2] = mean_aa; // unused
    aggregate_multi_k<<<2 * AGGBLK, 256, 0, stream>>>(A1);

    // ---- layer 1 GEMM ----
    GemmJobs G1;
    G1.A[0][0] = mean_aa; G1.Wf[0][0] = Wf[5];
    G1.A[0][1] = mean_ba; G1.Wf[0][1] = Wf[6];
    G1.A[0][2] = xa1;     G1.Wf[0][2] = Wf[7];
    G1.b0[0] = bn1_aa; G1.b1[0] = bn1_ba; G1.outp[0] = xa2; G1.nmats[0] = 3;
    G1.A[1][0] = nullptr; G1.Wf[1][0] = nullptr;
    G1.A[1][1] = nullptr; G1.Wf[1][1] = nullptr;
    G1.A[1][2] = nullptr; G1.Wf[1][2] = nullptr;
    G1.b0[1] = nullptr; G1.b1[1] = nullptr; G1.outp[1] = nullptr; G1.nmats[1] = 0;
    gemm_mfma_multi_k<<<GEMM_BLK, 256, 0, stream>>>(G1);

    // ---- pool + head ----
    pool_partial_k<<<(NA_N + 127) / 128, 256, 0, stream>>>(xa2, batch, pooled);
    out_head_k<<<1, 640, 0, stream>>>(pooled, batch, W_out, b_out, out);
}

// Round 8
// 457.277 us; speedup vs baseline: 2.7918x; 1.0179x over previous
//
#include <hip/hip_runtime.h>

#define NA_N 50000
#define NB_N 50000
#define NE   1000000
#define DF   128
#define NG_N 64
#define NC_N 10

// bucketed counting sort params
#define BSHIFT 7
#define BNODES 128
#define NBUK   391
#define CHB    4096
#define NIT    (CHB / 256)
#define BINBLK ((NE + CHB - 1) / CHB)    // 245
#define AGGBLK ((NA_N * 64) / 256)       // 12500 blocks per aggregation job

#define CN4A (NA_N * DF / 4)
#define CN4T ((NA_N + NB_N) * DF / 4)
#define WELEMS (8 * 16384)
#define PZ4 (NG_N * DF / 4)

typedef __attribute__((ext_vector_type(8))) short short8;
typedef __attribute__((ext_vector_type(4))) float float4v;

__device__ __forceinline__ unsigned short f2bf(float f) {
    unsigned u = __float_as_uint(f);
    unsigned r = (u + 0x7fff + ((u >> 16) & 1)) >> 16;   // RNE
    return (unsigned short)r;
}
__device__ __forceinline__ float bf_lo(unsigned d) { return __uint_as_float(d << 16); }
__device__ __forceinline__ float bf_hi(unsigned d) { return __uint_as_float(d & 0xffff0000u); }
__device__ __forceinline__ unsigned packbf(float lo, float hi) {
    return (unsigned)f2bf(lo) | ((unsigned)f2bf(hi) << 16);
}

// ---------------- fused prep: feature convert + weight prearrange + pooled zero ----------------

struct WJobs {
    const float* a[8];
    const float* b[8];
    unsigned short* d[8];
};

__global__ void prep_k(const float* __restrict__ xa, const float* __restrict__ xb,
                       unsigned short* __restrict__ ya, unsigned short* __restrict__ yb,
                       WJobs WJ, float* __restrict__ pooled) {
    int i = blockIdx.x * 256 + threadIdx.x;
    if (i < CN4T) {
        const float* x = (i < CN4A) ? xa : xb;
        unsigned short* y = (i < CN4A) ? ya : yb;
        int j = (i < CN4A) ? i : i - CN4A;
        float4 v = ((const float4*)x)[j];
        uint2 o;
        o.x = packbf(v.x, v.y);
        o.y = packbf(v.z, v.w);
        ((uint2*)y)[j] = o;
    } else if (i < CN4T + WELEMS) {
        int t = i - CN4T;
        int which = t >> 14;
        t &= 16383;
        int j = t & 7, lane = (t >> 3) & 63, k0i = (t >> 9) & 3, n0 = t >> 11;
        int k = k0i * 32 + (lane >> 4) * 8 + j;
        int n = n0 * 16 + (lane & 15);
        float v = WJ.a[which][k * DF + n];
        if (WJ.b[which]) v += WJ.b[which][k * DF + n];
        WJ.d[which][t] = f2bf(v);
    } else if (i < CN4T + WELEMS + PZ4) {
        int t = i - CN4T - WELEMS;
        ((float4*)pooled)[t] = (float4){0.f, 0.f, 0.f, 0.f};
    }
}

// ---------------- CSR build: 3 edge types batched per pass ----------------

struct CsrJobs {
    const int* src[3];
    const int* dst[3];
    int* offs[3];
    int* ss[3];
    unsigned* ebuf[3];
};

__global__ __launch_bounds__(256) void bucket_hist3_k(CsrJobs J, int* __restrict__ bcnt3) {
    int which = blockIdx.x / BINBLK;
    int blk = blockIdx.x % BINBLK;
    const int* dst = J.dst[which];
    int* bcnt = bcnt3 + which * NBUK;
    __shared__ int h[NBUK];
    for (int i = threadIdx.x; i < NBUK; i += 256) h[i] = 0;
    __syncthreads();
    int base = blk * CHB;
#pragma unroll
    for (int it = 0; it < NIT; it++) {
        int i = base + it * 256 + threadIdx.x;
        if (i < NE) atomicAdd(&h[dst[i] >> BSHIFT], 1);
    }
    __syncthreads();
    for (int i = threadIdx.x; i < NBUK; i += 256)
        if (h[i]) atomicAdd(&bcnt[i], h[i]);
}

__global__ void bucket_scan3_k(const int* __restrict__ bcnt3,
                               int* __restrict__ bbase3, int* __restrict__ bcur3) {
    __shared__ int s[512];
    int which = blockIdx.x;
    const int* bcnt = bcnt3 + which * NBUK;
    int* bbase = bbase3 + which * (NBUK + 1);
    int* bcur = bcur3 + which * NBUK;
    int t = threadIdx.x;
    int v = (t < NBUK) ? bcnt[t] : 0;
    s[t] = v;
    __syncthreads();
    for (int d = 1; d < 512; d <<= 1) {
        int x = (t >= d) ? s[t - d] : 0;
        __syncthreads();
        if (t >= d) s[t] += x;
        __syncthreads();
    }
    if (t < NBUK) {
        int e = s[t] - v;
        bbase[t] = e;
        bcur[t] = e;
    }
    if (t == 0) bbase[NBUK] = NE;
}

__global__ __launch_bounds__(256) void bucket_bin3_k(CsrJobs J, int* __restrict__ bcur3) {
    int which = blockIdx.x / BINBLK;
    int blk = blockIdx.x % BINBLK;
    const int* src = J.src[which];
    const int* dst = J.dst[which];
    int* bcur = bcur3 + which * NBUK;
    unsigned* ebuf = J.ebuf[which];
    __shared__ int cnt[NBUK];
    __shared__ int chunk[NBUK];
    for (int i = threadIdx.x; i < NBUK; i += 256) cnt[i] = 0;
    __syncthreads();
    int base = blk * CHB;
    int bk[NIT], rk[NIT];
    unsigned sv[NIT];
#pragma unroll
    for (int it = 0; it < NIT; it++) {
        int i = base + it * 256 + threadIdx.x;
        if (i < NE) {
            int d = dst[i];
            int b = d >> BSHIFT;
            bk[it] = b;
            rk[it] = atomicAdd(&cnt[b], 1);
            sv[it] = (unsigned)src[i] | ((unsigned)(d & (BNODES - 1)) << 24);
        } else {
            bk[it] = -1;
        }
    }
    __syncthreads();
    for (int i = threadIdx.x; i < NBUK; i += 256)
        chunk[i] = cnt[i] ? atomicAdd(&bcur[i], cnt[i]) : 0;
    __syncthreads();
#pragma unroll
    for (int it = 0; it < NIT; it++)
        if (bk[it] >= 0) ebuf[chunk[bk[it]] + rk[it]] = sv[it];
}

__global__ __launch_bounds__(256) void bucket_sort3_k(CsrJobs J, const int* __restrict__ bbase3,
                                                      int ndst) {
    __shared__ int hist[BNODES];
    __shared__ int loffs[BNODES];
    int which = blockIdx.x / NBUK;
    int b = blockIdx.x % NBUK;
    const unsigned* ebuf = J.ebuf[which];
    const int* bbase = bbase3 + which * (NBUK + 1);
    int* offs = J.offs[which];
    int* ss = J.ss[which];
    int t = threadIdx.x;
    int ebase = bbase[b], ecnt = bbase[b + 1] - ebase;
    if (t < BNODES) hist[t] = 0;
    __syncthreads();
    for (int e = t; e < ecnt; e += 256)
        atomicAdd(&hist[ebuf[ebase + e] >> 24], 1);
    __syncthreads();
    if (t < BNODES) loffs[t] = hist[t];
    __syncthreads();
    for (int d = 1; d < BNODES; d <<= 1) {
        int x = 0;
        if (t < BNODES && t >= d) x = loffs[t - d];
        __syncthreads();
        if (t < BNODES && t >= d) loffs[t] += x;
        __syncthreads();
    }
    if (t < BNODES) {
        int ex = loffs[t] - hist[t];
        loffs[t] = ex;
        int gnode = b * BNODES + t;
        if (gnode < ndst) offs[gnode] = ebase + ex;
        hist[t] = 0;
    }
    if (b == 0 && t == 0) offs[ndst] = NE;
    __syncthreads();
    for (int e = t; e < ecnt; e += 256) {
        unsigned w = ebuf[ebase + e];
        int dl = w >> 24;
        int r = atomicAdd(&hist[dl], 1);
        ss[ebase + loffs[dl] + r] = (int)(w & 0xFFFFFF);
    }
}

// ---------------- segment mean: index preload + UNIFORM-batch shfl ----------------
// 1 wave / dst node; one coalesced load grabs the node's first 64 edge indices.
// CORRECTNESS: all __shfl ops execute under a wave-uniform loop bound (dcap is
// wave-uniform), so source lanes are always active.  Loads are predicated by
// zero-init + conditional load; accumulating +0.0 is a numeric no-op.
// Subgroup of 16 lanes x 16B per row; 4 independent row loads in flight.

struct AggJobs {
    const unsigned short* xs[3];
    const int* offs[3];
    const int* ss[3];
    unsigned short* mean[3];
};

__global__ __launch_bounds__(256) void aggregate_multi_k(AggJobs J) {
    int job = blockIdx.x / AGGBLK;
    int blk = blockIdx.x % AGGBLK;
    int node = (blk * 256 + threadIdx.x) >> 6;
    int lane = threadIdx.x & 63;
    const unsigned* xs = (const unsigned*)J.xs[job];   // 64 dwords per row
    const int* offs = J.offs[job];
    const int* ss = J.ss[job];
    int o0 = offs[node], o1 = offs[node + 1];
    int deg = o1 - o0;
    int idx = (lane < deg) ? ss[o0 + lane] : 0;        // coalesced index preload
    int sub = lane >> 4;
    int q4 = (lane & 15) * 4;
    const unsigned* xq = xs + q4;                      // row s at xq + s*64
    float2 acc[4];
#pragma unroll
    for (int k = 0; k < 4; k++) acc[k] = (float2){0.f, 0.f};

    int dcap = deg < 64 ? deg : 64;
    // uniform batches of 16 edges (4 per subgroup)
    for (int b0 = 0; b0 < dcap; b0 += 16) {            // wave-uniform condition
        int e0 = b0 + sub;                              // source lanes <= 63 always
        int s0 = __shfl(idx, e0, 64);
        int s1 = __shfl(idx, e0 + 4, 64);
        int s2 = __shfl(idx, e0 + 8, 64);
        int s3 = __shfl(idx, e0 + 12, 64);
        uint4 u0 = {0u, 0u, 0u, 0u}, u1 = {0u, 0u, 0u, 0u};
        uint4 u2 = {0u, 0u, 0u, 0u}, u3 = {0u, 0u, 0u, 0u};
        if (e0 < dcap)      u0 = *(const uint4*)(xq + (size_t)s0 * 64);
        if (e0 + 4 < dcap)  u1 = *(const uint4*)(xq + (size_t)s1 * 64);
        if (e0 + 8 < dcap)  u2 = *(const uint4*)(xq + (size_t)s2 * 64);
        if (e0 + 12 < dcap) u3 = *(const uint4*)(xq + (size_t)s3 * 64);
        acc[0].x += bf_lo(u0.x); acc[0].y += bf_hi(u0.x);
        acc[1].x += bf_lo(u0.y); acc[1].y += bf_hi(u0.y);
        acc[2].x += bf_lo(u0.z); acc[2].y += bf_hi(u0.z);
        acc[3].x += bf_lo(u0.w); acc[3].y += bf_hi(u0.w);
        acc[0].x += bf_lo(u1.x); acc[0].y += bf_hi(u1.x);
        acc[1].x += bf_lo(u1.y); acc[1].y += bf_hi(u1.y);
        acc[2].x += bf_lo(u1.z); acc[2].y += bf_hi(u1.z);
        acc[3].x += bf_lo(u1.w); acc[3].y += bf_hi(u1.w);
        acc[0].x += bf_lo(u2.x); acc[0].y += bf_hi(u2.x);
        acc[1].x += bf_lo(u2.y); acc[1].y += bf_hi(u2.y);
        acc[2].x += bf_lo(u2.z); acc[2].y += bf_hi(u2.z);
        acc[3].x += bf_lo(u2.w); acc[3].y += bf_hi(u2.w);
        acc[0].x += bf_lo(u3.x); acc[0].y += bf_hi(u3.x);
        acc[1].x += bf_lo(u3.y); acc[1].y += bf_hi(u3.y);
        acc[2].x += bf_lo(u3.z); acc[2].y += bf_hi(u3.z);
        acc[3].x += bf_lo(u3.w); acc[3].y += bf_hi(u3.w);
    }
    // rare overflow path (deg > 64): direct index loads, no cross-lane ops
    for (int e2 = 64 + sub; e2 < deg; e2 += 4) {
        int s = ss[o0 + e2];
        uint4 u = *(const uint4*)(xq + (size_t)s * 64);
        acc[0].x += bf_lo(u.x); acc[0].y += bf_hi(u.x);
        acc[1].x += bf_lo(u.y); acc[1].y += bf_hi(u.y);
        acc[2].x += bf_lo(u.z); acc[2].y += bf_hi(u.z);
        acc[3].x += bf_lo(u.w); acc[3].y += bf_hi(u.w);
    }
#pragma unroll
    for (int k = 0; k < 4; k++) {
        acc[k].x += __shfl_down(acc[k].x, 32, 64);
        acc[k].y += __shfl_down(acc[k].y, 32, 64);
        acc[k].x += __shfl_down(acc[k].x, 16, 64);
        acc[k].y += __shfl_down(acc[k].y, 16, 64);
    }
    if (sub == 0) {
        int cnt = deg;
        float inv = 1.0f / (float)(cnt > 0 ? cnt : 1);
        uint4 o;
        o.x = packbf(acc[0].x * inv, acc[0].y * inv);
        o.y = packbf(acc[1].x * inv, acc[1].y * inv);
        o.z = packbf(acc[2].x * inv, acc[2].y * inv);
        o.w = packbf(acc[3].x * inv, acc[3].y * inv);
        *(uint4*)((unsigned*)J.mean[job] + (size_t)node * 64 + q4) = o;
    }
}

// ---------------- bf16 MFMA GEMM, up to 2 jobs per launch ----------------

struct GemmJobs {
    const unsigned short* A[2][3];
    const unsigned short* Wf[2][3];
    const float* b0[2];
    const float* b1[2];
    unsigned short* outp[2];
    int nmats[2];
};

#define GEMM_BLK ((NA_N + 127) / 128)    // 391 (NA_N == NB_N)

__global__ __launch_bounds__(256) void gemm_mfma_multi_k(GemmJobs J) {
    int job = blockIdx.x / GEMM_BLK;
    int blk = blockIdx.x % GEMM_BLK;
    const int nrows = NA_N;
    int lane = threadIdx.x & 63;
    int wv = threadIdx.x >> 6;
    int r0 = blk * 128 + wv * 32;
    int m = lane & 15, quad = lane >> 4;
    int rowA = r0 + m;      if (rowA >= nrows) rowA = nrows - 1;
    int rowB = r0 + 16 + m; if (rowB >= nrows) rowB = nrows - 1;
    int nmats = J.nmats[job];

    float4v acc0[8], acc1[8];
#pragma unroll
    for (int n0 = 0; n0 < 8; n0++) {
        acc0[n0] = (float4v){0.f, 0.f, 0.f, 0.f};
        acc1[n0] = (float4v){0.f, 0.f, 0.f, 0.f};
    }

    for (int mat = 0; mat < nmats; mat++) {
        const unsigned short* A  = J.A[job][mat];
        const unsigned short* Wf = J.Wf[job][mat];
#pragma unroll
        for (int k0i = 0; k0i < 4; k0i++) {
            short8 a0 = *(const short8*)(A + (size_t)rowA * DF + k0i * 32 + quad * 8);
            short8 a1 = *(const short8*)(A + (size_t)rowB * DF + k0i * 32 + quad * 8);
#pragma unroll
            for (int n0 = 0; n0 < 8; n0++) {
                short8 b = *(const short8*)(Wf + (((n0 * 4 + k0i) * 64 + lane) << 3));
                acc0[n0] = __builtin_amdgcn_mfma_f32_16x16x32_bf16(a0, b, acc0[n0], 0, 0, 0);
                acc1[n0] = __builtin_amdgcn_mfma_f32_16x16x32_bf16(a1, b, acc1[n0], 0, 0, 0);
            }
        }
    }

    const float* b0 = J.b0[job];
    const float* b1 = J.b1[job];
    unsigned short* out = J.outp[job];
#pragma unroll
    for (int n0 = 0; n0 < 8; n0++) {
        int c = n0 * 16 + m;
        float bb = b0[c] + (b1 ? b1[c] : 0.f);
#pragma unroll
        for (int i = 0; i < 4; i++) {
            int r = r0 + quad * 4 + i;
            if (r < nrows) out[(size_t)r * DF + c] = f2bf(fmaxf(acc0[n0][i] + bb, 0.f));
            int r2 = r0 + 16 + quad * 4 + i;
            if (r2 < nrows) out[(size_t)r2 * DF + c] = f2bf(fmaxf(acc1[n0][i] + bb, 0.f));
        }
    }
}

// ---------------- pooling + head ----------------

__device__ __forceinline__ int lb_search(const int* a, int n, int v) {
    int lo = 0, hi = n;
    while (lo < hi) {
        int mm = (lo + hi) >> 1;
        if (a[mm] < v) lo = mm + 1; else hi = mm;
    }
    return lo;
}

// 64 lanes x 4B (2 cols) per row, 4 row-ways per block of 128 rows
__global__ __launch_bounds__(256) void pool_partial_k(
    const unsigned short* __restrict__ xa, const int* __restrict__ batch,
    float* __restrict__ pooled) {
    int c2 = threadIdx.x & 63;              // dword (2 cols)
    int way = threadIdx.x >> 6;             // 0..3
    int row0 = blockIdx.x * 128;
    int rend = row0 + 128;
    if (rend > NA_N) rend = NA_N;
    const unsigned* x = (const unsigned*)xa;
    float2 acc = {0.f, 0.f};
    int cur_g = -1;
    for (int r = row0 + way; r < rend; r += 4) {
        int g = batch[r];
        if (g != cur_g) {
            if (cur_g >= 0) {
                atomicAdd(&pooled[cur_g * DF + c2 * 2], acc.x);
                atomicAdd(&pooled[cur_g * DF + c2 * 2 + 1], acc.y);
            }
            cur_g = g;
            acc = (float2){0.f, 0.f};
        }
        unsigned d = x[(size_t)r * 64 + c2];
        acc.x += bf_lo(d);
        acc.y += bf_hi(d);
    }
    if (cur_g >= 0) {
        atomicAdd(&pooled[cur_g * DF + c2 * 2], acc.x);
        atomicAdd(&pooled[cur_g * DF + c2 * 2 + 1], acc.y);
    }
}

__global__ void out_head_k(const float* __restrict__ pooled, const int* __restrict__ batch,
                           const float* __restrict__ Wout, const float* __restrict__ bout,
                           float* __restrict__ out) {
    int tid = threadIdx.x;
    if (tid >= NG_N * NC_N) return;
    int g = tid / NC_N, c = tid % NC_N;
    int lo = lb_search(batch, NA_N, g);
    int hi = lb_search(batch, NA_N, g + 1);
    int cnt = hi - lo;
    float inv = 1.0f / (float)(cnt > 0 ? cnt : 1);
    float s = 0.f;
    for (int k = 0; k < DF; k++) s += pooled[g * DF + k] * Wout[k * NC_N + c];
    out[tid] = s * inv + bout[c];
}

// ---------------- launcher ----------------

extern "C" void kernel_launch(void* const* d_in, const int* in_sizes, int n_in,
                              void* d_out, int out_size, void* d_ws, size_t ws_size,
                              hipStream_t stream) {
    const float* x_a = (const float*)d_in[0];
    const float* x_b = (const float*)d_in[1];
    const int* ei_aa = (const int*)d_in[2];
    const int* ei_ab = (const int*)d_in[3];
    const int* ei_ba = (const int*)d_in[4];
    const int* batch = (const int*)d_in[5];
    const float *Wn0_aa = (const float*)d_in[6],  *bn0_aa = (const float*)d_in[7],  *Wr0_aa = (const float*)d_in[8];
    const float *Wn0_ab = (const float*)d_in[9],  *bn0_ab = (const float*)d_in[10], *Wr0_ab = (const float*)d_in[11];
    const float *Wn0_ba = (const float*)d_in[12], *bn0_ba = (const float*)d_in[13], *Wr0_ba = (const float*)d_in[14];
    const float *Wn1_aa = (const float*)d_in[15], *bn1_aa = (const float*)d_in[16], *Wr1_aa = (const float*)d_in[17];
    // d_in[18..20] unused (layer-2 out_b never consumed)
    const float *Wn1_ba = (const float*)d_in[21], *bn1_ba = (const float*)d_in[22], *Wr1_ba = (const float*)d_in[23];
    const float *W_out = (const float*)d_in[24], *b_out = (const float*)d_in[25];
    float* out = (float*)d_out;

    char* w = (char*)d_ws;
    size_t off = 0;
    auto alloc = [&](size_t b) -> char* {
        char* p = w + off;
        off += (b + 255) & ~(size_t)255;
        return p;
    };

    int* offs_aa = (int*)alloc((NA_N + 1) * 4);
    int* ss_aa   = (int*)alloc((size_t)NE * 4);
    int* offs_ba = (int*)alloc((NA_N + 1) * 4);
    int* ss_ba   = (int*)alloc((size_t)NE * 4);
    int* offs_ab = (int*)alloc((NB_N + 1) * 4);
    int* ss_ab   = (int*)alloc((size_t)NE * 4);
    int* bcnt3  = (int*)alloc(3 * NBUK * 4);
    int* bbase3 = (int*)alloc(3 * (NBUK + 1) * 4);
    int* bcur3  = (int*)alloc(3 * NBUK * 4);
    unsigned* ebuf0 = (unsigned*)alloc((size_t)NE * 4);
    unsigned* ebuf1 = (unsigned*)alloc((size_t)NE * 4);
    unsigned* ebuf2 = (unsigned*)alloc((size_t)NE * 4);

    unsigned short* xa_bf   = (unsigned short*)alloc((size_t)NA_N * DF * 2);
    unsigned short* xb_bf   = (unsigned short*)alloc((size_t)NB_N * DF * 2);
    unsigned short* mean_aa = (unsigned short*)alloc((size_t)NA_N * DF * 2);
    unsigned short* mean_ba = (unsigned short*)alloc((size_t)NA_N * DF * 2);
    unsigned short* mean_ab = (unsigned short*)alloc((size_t)NB_N * DF * 2);
    unsigned short* xa1 = (unsigned short*)alloc((size_t)NA_N * DF * 2);
    unsigned short* xb1 = (unsigned short*)alloc((size_t)NB_N * DF * 2);
    unsigned short* xa2 = mean_ab;  // alias: mean_ab dead once layer-0 dst-b GEMM ran
    unsigned short* Wf[8];
    for (int i = 0; i < 8; i++) Wf[i] = (unsigned short*)alloc((size_t)DF * DF * 2);
    float* pooled = (float*)alloc(NG_N * DF * 4);

    // ---- CSR build (3 edge types batched) ----
    CsrJobs CJ;
    CJ.src[0] = ei_aa;      CJ.dst[0] = ei_aa + NE;
    CJ.src[1] = ei_ba;      CJ.dst[1] = ei_ba + NE;
    CJ.src[2] = ei_ab;      CJ.dst[2] = ei_ab + NE;
    CJ.offs[0] = offs_aa;   CJ.ss[0] = ss_aa;   CJ.ebuf[0] = ebuf0;
    CJ.offs[1] = offs_ba;   CJ.ss[1] = ss_ba;   CJ.ebuf[1] = ebuf1;
    CJ.offs[2] = offs_ab;   CJ.ss[2] = ss_ab;   CJ.ebuf[2] = ebuf2;

    hipMemsetAsync(bcnt3, 0, 3 * NBUK * sizeof(int), stream);
    bucket_hist3_k<<<3 * BINBLK, 256, 0, stream>>>(CJ, bcnt3);
    bucket_scan3_k<<<3, 512, 0, stream>>>(bcnt3, bbase3, bcur3);
    bucket_bin3_k<<<3 * BINBLK, 256, 0, stream>>>(CJ, bcur3);
    bucket_sort3_k<<<3 * NBUK, 256, 0, stream>>>(CJ, bbase3, NA_N);

    // ---- fused prep: converts + weight prearrange (Wr pairs summed) + pooled zero ----
    WJobs WJ;
    WJ.a[0] = Wn0_aa; WJ.b[0] = nullptr; WJ.d[0] = Wf[0];
    WJ.a[1] = Wn0_ba; WJ.b[1] = nullptr; WJ.d[1] = Wf[1];
    WJ.a[2] = Wr0_aa; WJ.b[2] = Wr0_ba;  WJ.d[2] = Wf[2];
    WJ.a[3] = Wn0_ab; WJ.b[3] = nullptr; WJ.d[3] = Wf[3];
    WJ.a[4] = Wr0_ab; WJ.b[4] = nullptr; WJ.d[4] = Wf[4];
    WJ.a[5] = Wn1_aa; WJ.b[5] = nullptr; WJ.d[5] = Wf[5];
    WJ.a[6] = Wn1_ba; WJ.b[6] = nullptr; WJ.d[6] = Wf[6];
    WJ.a[7] = Wr1_aa; WJ.b[7] = Wr1_ba;  WJ.d[7] = Wf[7];
    const int PREP_ITEMS = CN4T + WELEMS + PZ4;
    prep_k<<<(PREP_ITEMS + 255) / 256, 256, 0, stream>>>(x_a, x_b, xa_bf, xb_bf, WJ, pooled);

    // ---- layer 0: 3 aggregations fused ----
    AggJobs A0;
    A0.xs[0] = xa_bf; A0.offs[0] = offs_aa; A0.ss[0] = ss_aa; A0.mean[0] = mean_aa;
    A0.xs[1] = xb_bf; A0.offs[1] = offs_ba; A0.ss[1] = ss_ba; A0.mean[1] = mean_ba;
    A0.xs[2] = xa_bf; A0.offs[2] = offs_ab; A0.ss[2] = ss_ab; A0.mean[2] = mean_ab;
    aggregate_multi_k<<<3 * AGGBLK, 256, 0, stream>>>(A0);

    // ---- layer 0: both GEMMs in one launch ----
    GemmJobs G0;
    G0.A[0][0] = mean_aa; G0.Wf[0][0] = Wf[0];
    G0.A[0][1] = mean_ba; G0.Wf[0][1] = Wf[1];
    G0.A[0][2] = xa_bf;   G0.Wf[0][2] = Wf[2];
    G0.b0[0] = bn0_aa; G0.b1[0] = bn0_ba; G0.outp[0] = xa1; G0.nmats[0] = 3;
    G0.A[1][0] = mean_ab; G0.Wf[1][0] = Wf[3];
    G0.A[1][1] = xb_bf;   G0.Wf[1][1] = Wf[4];
    G0.A[1][2] = nullptr; G0.Wf[1][2] = nullptr;
    G0.b0[1] = bn0_ab; G0.b1[1] = nullptr; G0.outp[1] = xb1; G0.nmats[1] = 2;
    gemm_mfma_multi_k<<<2 * GEMM_BLK, 256, 0, stream>>>(G0);

    // ---- layer 1: 2 aggregations fused (out_b unused downstream -> skipped) ----
    AggJobs A1;
    A1.xs[0] = xa1; A1.offs[0] = offs_aa; A1.ss[0] = ss_aa; A1.mean[0] = mean_aa;
    A1.xs[1] = xb1; A1.offs[1] = offs_ba; A1.ss[1] = ss_ba; A1.mean[1] = mean_ba;
    A1.xs[2] = xa1; A1.offs[2] = offs_aa; A1.ss[2] = ss_aa; A1.mean[2] = mean_aa; // unused
    aggregate_multi_k<<<2 * AGGBLK, 256, 0, stream>>>(A1);

    // ---- layer 1 GEMM ----
    GemmJobs G1;
    G1.A[0][0] = mean_aa; G1.Wf[0][0] = Wf[5];
    G1.A[0][1] = mean_ba; G1.Wf[0][1] = Wf[6];
    G1.A[0][2] = xa1;     G1.Wf[0][2] = Wf[7];
    G1.b0[0] = bn1_aa; G1.b1[0] = bn1_ba; G1.outp[0] = xa2; G1.nmats[0] = 3;
    G1.A[1][0] = nullptr; G1.Wf[1][0] = nullptr;
    G1.A[1][1] = nullptr; G1.Wf[1][1] = nullptr;
    G1.A[1][2] = nullptr; G1.Wf[1][2] = nullptr;
    G1.b0[1] = nullptr; G1.b1[1] = nullptr; G1.outp[1] = nullptr; G1.nmats[1] = 0;
    gemm_mfma_multi_k<<<GEMM_BLK, 256, 0, stream>>>(G1);

    // ---- pool + head ----
    pool_partial_k<<<(NA_N + 127) / 128, 256, 0, stream>>>(xa2, batch, pooled);
    out_head_k<<<1, 640, 0, stream>>>(pooled, batch, W_out, b_out, out);
}

// Round 9
// 446.987 us; speedup vs baseline: 2.8561x; 1.0230x over previous
//
#include <hip/hip_runtime.h>

#define NA_N 50000
#define NB_N 50000
#define NE   1000000
#define DF   128
#define NG_N 64
#define NC_N 10

// bucketed counting sort params
#define BSHIFT 7
#define BNODES 128
#define NBUK   391
#define CHB    4096
#define NIT    (CHB / 256)
#define BINBLK ((NE + CHB - 1) / CHB)    // 245
#define AGGBLK ((NA_N * 64) / 256)       // 12500 blocks per aggregation job

#define CN4A (NA_N * DF / 4)
#define CN4T ((NA_N + NB_N) * DF / 4)
#define WELEMS (8 * 16384)
#define PZ4 (NG_N * DF / 4)
#define PREP_BLKS ((CN4T + WELEMS + PZ4 + 255) / 256)

// XCD-partitioned aggregation grids (b&7 ~ XCD heuristic; perf-only)
#define AGG0_GRID 40000                  // 8 * 5000; jobs{0,2}(xa) on xcd 0-4, job1(xb) on 5-7
#define AGG1_GRID 25000                  // 8 * 3125; job0 on xcd 0-3, job1 on 4-7

typedef __attribute__((ext_vector_type(8))) short short8;
typedef __attribute__((ext_vector_type(4))) float float4v;

__device__ __forceinline__ unsigned short f2bf(float f) {
    unsigned u = __float_as_uint(f);
    unsigned r = (u + 0x7fff + ((u >> 16) & 1)) >> 16;   // RNE
    return (unsigned short)r;
}
__device__ __forceinline__ float bf_lo(unsigned d) { return __uint_as_float(d << 16); }
__device__ __forceinline__ float bf_hi(unsigned d) { return __uint_as_float(d & 0xffff0000u); }
__device__ __forceinline__ unsigned packbf(float lo, float hi) {
    return (unsigned)f2bf(lo) | ((unsigned)f2bf(hi) << 16);
}

struct WJobs {
    const float* a[8];
    const float* b[8];
    unsigned short* d[8];
};

struct CsrJobs {
    const int* src[3];
    const int* dst[3];
    int* offs[3];
    int* ss[3];
    unsigned* ebuf[3];
};

// ---------------- fused prep (convert + weight prearrange + pooled zero) + bucket hist ----------------

__global__ __launch_bounds__(256) void prep_hist_k(
        const float* __restrict__ xa, const float* __restrict__ xb,
        unsigned short* __restrict__ ya, unsigned short* __restrict__ yb,
        WJobs WJ, float* __restrict__ pooled,
        CsrJobs CJ, int* __restrict__ bcnt3) {
    if ((int)blockIdx.x < PREP_BLKS) {
        int i = blockIdx.x * 256 + threadIdx.x;
        if (i < CN4T) {
            const float* x = (i < CN4A) ? xa : xb;
            unsigned short* y = (i < CN4A) ? ya : yb;
            int j = (i < CN4A) ? i : i - CN4A;
            float4 v = ((const float4*)x)[j];
            uint2 o;
            o.x = packbf(v.x, v.y);
            o.y = packbf(v.z, v.w);
            ((uint2*)y)[j] = o;
        } else if (i < CN4T + WELEMS) {
            int t = i - CN4T;
            int which = t >> 14;
            t &= 16383;
            int j = t & 7, lane = (t >> 3) & 63, k0i = (t >> 9) & 3, n0 = t >> 11;
            int k = k0i * 32 + (lane >> 4) * 8 + j;
            int n = n0 * 16 + (lane & 15);
            float v = WJ.a[which][k * DF + n];
            if (WJ.b[which]) v += WJ.b[which][k * DF + n];
            WJ.d[which][t] = f2bf(v);
        } else if (i < CN4T + WELEMS + PZ4) {
            int t = i - CN4T - WELEMS;
            ((float4*)pooled)[t] = (float4){0.f, 0.f, 0.f, 0.f};
        }
        return;
    }
    // bucket histogram part
    int hb = blockIdx.x - PREP_BLKS;
    int which = hb / BINBLK;
    int blk = hb % BINBLK;
    const int* dst = CJ.dst[which];
    int* bcnt = bcnt3 + which * NBUK;
    __shared__ int h[NBUK];
    for (int i = threadIdx.x; i < NBUK; i += 256) h[i] = 0;
    __syncthreads();
    int base = blk * CHB;
#pragma unroll
    for (int it = 0; it < NIT; it++) {
        int i = base + it * 256 + threadIdx.x;
        if (i < NE) atomicAdd(&h[dst[i] >> BSHIFT], 1);
    }
    __syncthreads();
    for (int i = threadIdx.x; i < NBUK; i += 256)
        if (h[i]) atomicAdd(&bcnt[i], h[i]);
}

// ---------------- CSR build (scan / bin / sort) ----------------

__global__ void bucket_scan3_k(const int* __restrict__ bcnt3,
                               int* __restrict__ bbase3, int* __restrict__ bcur3) {
    __shared__ int s[512];
    int which = blockIdx.x;
    const int* bcnt = bcnt3 + which * NBUK;
    int* bbase = bbase3 + which * (NBUK + 1);
    int* bcur = bcur3 + which * NBUK;
    int t = threadIdx.x;
    int v = (t < NBUK) ? bcnt[t] : 0;
    s[t] = v;
    __syncthreads();
    for (int d = 1; d < 512; d <<= 1) {
        int x = (t >= d) ? s[t - d] : 0;
        __syncthreads();
        if (t >= d) s[t] += x;
        __syncthreads();
    }
    if (t < NBUK) {
        int e = s[t] - v;
        bbase[t] = e;
        bcur[t] = e;
    }
    if (t == 0) bbase[NBUK] = NE;
}

__global__ __launch_bounds__(256) void bucket_bin3_k(CsrJobs J, int* __restrict__ bcur3) {
    int which = blockIdx.x / BINBLK;
    int blk = blockIdx.x % BINBLK;
    const int* src = J.src[which];
    const int* dst = J.dst[which];
    int* bcur = bcur3 + which * NBUK;
    unsigned* ebuf = J.ebuf[which];
    __shared__ int cnt[NBUK];
    __shared__ int chunk[NBUK];
    for (int i = threadIdx.x; i < NBUK; i += 256) cnt[i] = 0;
    __syncthreads();
    int base = blk * CHB;
    int bk[NIT], rk[NIT];
    unsigned sv[NIT];
#pragma unroll
    for (int it = 0; it < NIT; it++) {
        int i = base + it * 256 + threadIdx.x;
        if (i < NE) {
            int d = dst[i];
            int b = d >> BSHIFT;
            bk[it] = b;
            rk[it] = atomicAdd(&cnt[b], 1);
            sv[it] = (unsigned)src[i] | ((unsigned)(d & (BNODES - 1)) << 24);
        } else {
            bk[it] = -1;
        }
    }
    __syncthreads();
    for (int i = threadIdx.x; i < NBUK; i += 256)
        chunk[i] = cnt[i] ? atomicAdd(&bcur[i], cnt[i]) : 0;
    __syncthreads();
#pragma unroll
    for (int it = 0; it < NIT; it++)
        if (bk[it] >= 0) ebuf[chunk[bk[it]] + rk[it]] = sv[it];
}

__global__ __launch_bounds__(256) void bucket_sort3_k(CsrJobs J, const int* __restrict__ bbase3,
                                                      int ndst) {
    __shared__ int hist[BNODES];
    __shared__ int loffs[BNODES];
    int which = blockIdx.x / NBUK;
    int b = blockIdx.x % NBUK;
    const unsigned* ebuf = J.ebuf[which];
    const int* bbase = bbase3 + which * (NBUK + 1);
    int* offs = J.offs[which];
    int* ss = J.ss[which];
    int t = threadIdx.x;
    int ebase = bbase[b], ecnt = bbase[b + 1] - ebase;
    if (t < BNODES) hist[t] = 0;
    __syncthreads();
    for (int e = t; e < ecnt; e += 256)
        atomicAdd(&hist[ebuf[ebase + e] >> 24], 1);
    __syncthreads();
    if (t < BNODES) loffs[t] = hist[t];
    __syncthreads();
    for (int d = 1; d < BNODES; d <<= 1) {
        int x = 0;
        if (t < BNODES && t >= d) x = loffs[t - d];
        __syncthreads();
        if (t < BNODES && t >= d) loffs[t] += x;
        __syncthreads();
    }
    if (t < BNODES) {
        int ex = loffs[t] - hist[t];
        loffs[t] = ex;
        int gnode = b * BNODES + t;
        if (gnode < ndst) offs[gnode] = ebase + ex;
        hist[t] = 0;
    }
    if (b == 0 && t == 0) offs[ndst] = NE;
    __syncthreads();
    for (int e = t; e < ecnt; e += 256) {
        unsigned w = ebuf[ebase + e];
        int dl = w >> 24;
        int r = atomicAdd(&hist[dl], 1);
        ss[ebase + loffs[dl] + r] = (int)(w & 0xFFFFFF);
    }
}

// ---------------- segment mean: XCD-partitioned jobs, full/tail batch split ----------------
// 1 wave / dst node; indices preloaded + distributed via __shfl under wave-uniform
// control flow (R7 lesson).  Main loop = full 16-edge batches, unconditional loads;
// single predicated tail batch.  Job->block mapping groups each feature table's
// readers onto a subset of XCDs (blockIdx&7 heuristic) to cut L2-fill traffic.

struct AggJobs {
    const unsigned short* xs[3];
    const int* offs[3];
    const int* ss[3];
    unsigned short* mean[3];
};

__device__ __forceinline__ void agg_batch_full(const unsigned* xq, int idx, int e0,
                                               float2 acc[4]) {
    int s0 = __shfl(idx, e0, 64);
    int s1 = __shfl(idx, e0 + 4, 64);
    int s2 = __shfl(idx, e0 + 8, 64);
    int s3 = __shfl(idx, e0 + 12, 64);
    uint4 u0 = *(const uint4*)(xq + (size_t)s0 * 64);
    uint4 u1 = *(const uint4*)(xq + (size_t)s1 * 64);
    uint4 u2 = *(const uint4*)(xq + (size_t)s2 * 64);
    uint4 u3 = *(const uint4*)(xq + (size_t)s3 * 64);
    acc[0].x += bf_lo(u0.x); acc[0].y += bf_hi(u0.x);
    acc[1].x += bf_lo(u0.y); acc[1].y += bf_hi(u0.y);
    acc[2].x += bf_lo(u0.z); acc[2].y += bf_hi(u0.z);
    acc[3].x += bf_lo(u0.w); acc[3].y += bf_hi(u0.w);
    acc[0].x += bf_lo(u1.x); acc[0].y += bf_hi(u1.x);
    acc[1].x += bf_lo(u1.y); acc[1].y += bf_hi(u1.y);
    acc[2].x += bf_lo(u1.z); acc[2].y += bf_hi(u1.z);
    acc[3].x += bf_lo(u1.w); acc[3].y += bf_hi(u1.w);
    acc[0].x += bf_lo(u2.x); acc[0].y += bf_hi(u2.x);
    acc[1].x += bf_lo(u2.y); acc[1].y += bf_hi(u2.y);
    acc[2].x += bf_lo(u2.z); acc[2].y += bf_hi(u2.z);
    acc[3].x += bf_lo(u2.w); acc[3].y += bf_hi(u2.w);
    acc[0].x += bf_lo(u3.x); acc[0].y += bf_hi(u3.x);
    acc[1].x += bf_lo(u3.y); acc[1].y += bf_hi(u3.y);
    acc[2].x += bf_lo(u3.z); acc[2].y += bf_hi(u3.z);
    acc[3].x += bf_lo(u3.w); acc[3].y += bf_hi(u3.w);
}

__global__ __launch_bounds__(256) void aggregate_multi_k(AggJobs J, int njobs) {
    int b = blockIdx.x;
    int xcd = b & 7, local = b >> 3;
    int job, blk;
    if (njobs == 3) {                     // grid 40000: local in [0,5000)
        if (xcd < 5) {                    // xa-reading jobs 0 and 2
            int L = xcd * 5000 + local;   // [0,25000)
            job = (L < AGGBLK) ? 0 : 2;
            blk = (L < AGGBLK) ? L : L - AGGBLK;
        } else {                          // xb-reading job 1
            int L = (xcd - 5) * 5000 + local;   // [0,15000)
            if (L >= AGGBLK) return;
            job = 1;
            blk = L;
        }
    } else {                              // grid 25000: local in [0,3125)
        if (xcd < 4) { job = 0; blk = xcd * 3125 + local; }
        else         { job = 1; blk = (xcd - 4) * 3125 + local; }
    }

    int node = (blk * 256 + threadIdx.x) >> 6;
    int lane = threadIdx.x & 63;
    const unsigned* xs = (const unsigned*)J.xs[job];   // 64 dwords per row
    const int* offs = J.offs[job];
    const int* ss = J.ss[job];
    int o0 = offs[node], o1 = offs[node + 1];
    int deg = o1 - o0;
    int idx = (lane < deg) ? ss[o0 + lane] : 0;        // coalesced index preload
    int sub = lane >> 4;
    int q4 = (lane & 15) * 4;
    const unsigned* xq = xs + q4;                      // row s at xq + s*64
    float2 acc[4];
#pragma unroll
    for (int k = 0; k < 4; k++) acc[k] = (float2){0.f, 0.f};

    int dcap = deg < 64 ? deg : 64;
    int full = dcap & ~15;                             // wave-uniform
    int b0 = 0;
    for (; b0 < full; b0 += 16)                        // unconditional loads
        agg_batch_full(xq, idx, b0 + sub, acc);
    if (b0 < dcap) {                                   // single predicated tail
        int e0 = b0 + sub;
        int s0 = __shfl(idx, e0, 64);
        int s1 = __shfl(idx, e0 + 4, 64);
        int s2 = __shfl(idx, e0 + 8, 64);
        int s3 = __shfl(idx, e0 + 12, 64);
        uint4 u0 = {0u, 0u, 0u, 0u}, u1 = {0u, 0u, 0u, 0u};
        uint4 u2 = {0u, 0u, 0u, 0u}, u3 = {0u, 0u, 0u, 0u};
        if (e0 < dcap)      u0 = *(const uint4*)(xq + (size_t)s0 * 64);
        if (e0 + 4 < dcap)  u1 = *(const uint4*)(xq + (size_t)s1 * 64);
        if (e0 + 8 < dcap)  u2 = *(const uint4*)(xq + (size_t)s2 * 64);
        if (e0 + 12 < dcap) u3 = *(const uint4*)(xq + (size_t)s3 * 64);
        acc[0].x += bf_lo(u0.x); acc[0].y += bf_hi(u0.x);
        acc[1].x += bf_lo(u0.y); acc[1].y += bf_hi(u0.y);
        acc[2].x += bf_lo(u0.z); acc[2].y += bf_hi(u0.z);
        acc[3].x += bf_lo(u0.w); acc[3].y += bf_hi(u0.w);
        acc[0].x += bf_lo(u1.x); acc[0].y += bf_hi(u1.x);
        acc[1].x += bf_lo(u1.y); acc[1].y += bf_hi(u1.y);
        acc[2].x += bf_lo(u1.z); acc[2].y += bf_hi(u1.z);
        acc[3].x += bf_lo(u1.w); acc[3].y += bf_hi(u1.w);
        acc[0].x += bf_lo(u2.x); acc[0].y += bf_hi(u2.x);
        acc[1].x += bf_lo(u2.y); acc[1].y += bf_hi(u2.y);
        acc[2].x += bf_lo(u2.z); acc[2].y += bf_hi(u2.z);
        acc[3].x += bf_lo(u2.w); acc[3].y += bf_hi(u2.w);
        acc[0].x += bf_lo(u3.x); acc[0].y += bf_hi(u3.x);
        acc[1].x += bf_lo(u3.y); acc[1].y += bf_hi(u3.y);
        acc[2].x += bf_lo(u3.z); acc[2].y += bf_hi(u3.z);
        acc[3].x += bf_lo(u3.w); acc[3].y += bf_hi(u3.w);
    }
    // rare overflow path (deg > 64): direct index loads, no cross-lane ops
    for (int e2 = 64 + sub; e2 < deg; e2 += 4) {
        int s = ss[o0 + e2];
        uint4 u = *(const uint4*)(xq + (size_t)s * 64);
        acc[0].x += bf_lo(u.x); acc[0].y += bf_hi(u.x);
        acc[1].x += bf_lo(u.y); acc[1].y += bf_hi(u.y);
        acc[2].x += bf_lo(u.z); acc[2].y += bf_hi(u.z);
        acc[3].x += bf_lo(u.w); acc[3].y += bf_hi(u.w);
    }
#pragma unroll
    for (int k = 0; k < 4; k++) {
        acc[k].x += __shfl_down(acc[k].x, 32, 64);
        acc[k].y += __shfl_down(acc[k].y, 32, 64);
        acc[k].x += __shfl_down(acc[k].x, 16, 64);
        acc[k].y += __shfl_down(acc[k].y, 16, 64);
    }
    if (sub == 0) {
        float inv = 1.0f / (float)(deg > 0 ? deg : 1);
        uint4 o;
        o.x = packbf(acc[0].x * inv, acc[0].y * inv);
        o.y = packbf(acc[1].x * inv, acc[1].y * inv);
        o.z = packbf(acc[2].x * inv, acc[2].y * inv);
        o.w = packbf(acc[3].x * inv, acc[3].y * inv);
        *(uint4*)((unsigned*)J.mean[job] + (size_t)node * 64 + q4) = o;
    }
}

// ---------------- bf16 MFMA GEMM, up to 2 jobs per launch ----------------

struct GemmJobs {
    const unsigned short* A[2][3];
    const unsigned short* Wf[2][3];
    const float* b0[2];
    const float* b1[2];
    unsigned short* outp[2];
    int nmats[2];
};

#define GEMM_BLK ((NA_N + 127) / 128)    // 391 (NA_N == NB_N)

__global__ __launch_bounds__(256) void gemm_mfma_multi_k(GemmJobs J) {
    int job = blockIdx.x / GEMM_BLK;
    int blk = blockIdx.x % GEMM_BLK;
    const int nrows = NA_N;
    int lane = threadIdx.x & 63;
    int wv = threadIdx.x >> 6;
    int r0 = blk * 128 + wv * 32;
    int m = lane & 15, quad = lane >> 4;
    int rowA = r0 + m;      if (rowA >= nrows) rowA = nrows - 1;
    int rowB = r0 + 16 + m; if (rowB >= nrows) rowB = nrows - 1;
    int nmats = J.nmats[job];

    float4v acc0[8], acc1[8];
#pragma unroll
    for (int n0 = 0; n0 < 8; n0++) {
        acc0[n0] = (float4v){0.f, 0.f, 0.f, 0.f};
        acc1[n0] = (float4v){0.f, 0.f, 0.f, 0.f};
    }

    for (int mat = 0; mat < nmats; mat++) {
        const unsigned short* A  = J.A[job][mat];
        const unsigned short* Wf = J.Wf[job][mat];
#pragma unroll
        for (int k0i = 0; k0i < 4; k0i++) {
            short8 a0 = *(const short8*)(A + (size_t)rowA * DF + k0i * 32 + quad * 8);
            short8 a1 = *(const short8*)(A + (size_t)rowB * DF + k0i * 32 + quad * 8);
#pragma unroll
            for (int n0 = 0; n0 < 8; n0++) {
                short8 b = *(const short8*)(Wf + (((n0 * 4 + k0i) * 64 + lane) << 3));
                acc0[n0] = __builtin_amdgcn_mfma_f32_16x16x32_bf16(a0, b, acc0[n0], 0, 0, 0);
                acc1[n0] = __builtin_amdgcn_mfma_f32_16x16x32_bf16(a1, b, acc1[n0], 0, 0, 0);
            }
        }
    }

    const float* b0 = J.b0[job];
    const float* b1 = J.b1[job];
    unsigned short* out = J.outp[job];
#pragma unroll
    for (int n0 = 0; n0 < 8; n0++) {
        int c = n0 * 16 + m;
        float bb = b0[c] + (b1 ? b1[c] : 0.f);
#pragma unroll
        for (int i = 0; i < 4; i++) {
            int r = r0 + quad * 4 + i;
            if (r < nrows) out[(size_t)r * DF + c] = f2bf(fmaxf(acc0[n0][i] + bb, 0.f));
            int r2 = r0 + 16 + quad * 4 + i;
            if (r2 < nrows) out[(size_t)r2 * DF + c] = f2bf(fmaxf(acc1[n0][i] + bb, 0.f));
        }
    }
}

// ---------------- pooling + head ----------------

__device__ __forceinline__ int lb_search(const int* a, int n, int v) {
    int lo = 0, hi = n;
    while (lo < hi) {
        int mm = (lo + hi) >> 1;
        if (a[mm] < v) lo = mm + 1; else hi = mm;
    }
    return lo;
}

__global__ __launch_bounds__(256) void pool_partial_k(
    const unsigned short* __restrict__ xa, const int* __restrict__ batch,
    float* __restrict__ pooled) {
    int c2 = threadIdx.x & 63;
    int way = threadIdx.x >> 6;
    int row0 = blockIdx.x * 128;
    int rend = row0 + 128;
    if (rend > NA_N) rend = NA_N;
    const unsigned* x = (const unsigned*)xa;
    float2 acc = {0.f, 0.f};
    int cur_g = -1;
    for (int r = row0 + way; r < rend; r += 4) {
        int g = batch[r];
        if (g != cur_g) {
            if (cur_g >= 0) {
                atomicAdd(&pooled[cur_g * DF + c2 * 2], acc.x);
                atomicAdd(&pooled[cur_g * DF + c2 * 2 + 1], acc.y);
            }
            cur_g = g;
            acc = (float2){0.f, 0.f};
        }
        unsigned d = x[(size_t)r * 64 + c2];
        acc.x += bf_lo(d);
        acc.y += bf_hi(d);
    }
    if (cur_g >= 0) {
        atomicAdd(&pooled[cur_g * DF + c2 * 2], acc.x);
        atomicAdd(&pooled[cur_g * DF + c2 * 2 + 1], acc.y);
    }
}

__global__ void out_head_k(const float* __restrict__ pooled, const int* __restrict__ batch,
                           const float* __restrict__ Wout, const float* __restrict__ bout,
                           float* __restrict__ out) {
    int tid = threadIdx.x;
    if (tid >= NG_N * NC_N) return;
    int g = tid / NC_N, c = tid % NC_N;
    int lo = lb_search(batch, NA_N, g);
    int hi = lb_search(batch, NA_N, g + 1);
    int cnt = hi - lo;
    float inv = 1.0f / (float)(cnt > 0 ? cnt : 1);
    float s = 0.f;
    for (int k = 0; k < DF; k++) s += pooled[g * DF + k] * Wout[k * NC_N + c];
    out[tid] = s * inv + bout[c];
}

// ---------------- launcher ----------------

extern "C" void kernel_launch(void* const* d_in, const int* in_sizes, int n_in,
                              void* d_out, int out_size, void* d_ws, size_t ws_size,
                              hipStream_t stream) {
    const float* x_a = (const float*)d_in[0];
    const float* x_b = (const float*)d_in[1];
    const int* ei_aa = (const int*)d_in[2];
    const int* ei_ab = (const int*)d_in[3];
    const int* ei_ba = (const int*)d_in[4];
    const int* batch = (const int*)d_in[5];
    const float *Wn0_aa = (const float*)d_in[6],  *bn0_aa = (const float*)d_in[7],  *Wr0_aa = (const float*)d_in[8];
    const float *Wn0_ab = (const float*)d_in[9],  *bn0_ab = (const float*)d_in[10], *Wr0_ab = (const float*)d_in[11];
    const float *Wn0_ba = (const float*)d_in[12], *bn0_ba = (const float*)d_in[13], *Wr0_ba = (const float*)d_in[14];
    const float *Wn1_aa = (const float*)d_in[15], *bn1_aa = (const float*)d_in[16], *Wr1_aa = (const float*)d_in[17];
    // d_in[18..20] unused (layer-2 out_b never consumed)
    const float *Wn1_ba = (const float*)d_in[21], *bn1_ba = (const float*)d_in[22], *Wr1_ba = (const float*)d_in[23];
    const float *W_out = (const float*)d_in[24], *b_out = (const float*)d_in[25];
    float* out = (float*)d_out;

    char* w = (char*)d_ws;
    size_t off = 0;
    auto alloc = [&](size_t b) -> char* {
        char* p = w + off;
        off += (b + 255) & ~(size_t)255;
        return p;
    };

    int* offs_aa = (int*)alloc((NA_N + 1) * 4);
    int* ss_aa   = (int*)alloc((size_t)NE * 4);
    int* offs_ba = (int*)alloc((NA_N + 1) * 4);
    int* ss_ba   = (int*)alloc((size_t)NE * 4);
    int* offs_ab = (int*)alloc((NB_N + 1) * 4);
    int* ss_ab   = (int*)alloc((size_t)NE * 4);
    int* bcnt3  = (int*)alloc(3 * NBUK * 4);
    int* bbase3 = (int*)alloc(3 * (NBUK + 1) * 4);
    int* bcur3  = (int*)alloc(3 * NBUK * 4);
    unsigned* ebuf0 = (unsigned*)alloc((size_t)NE * 4);
    unsigned* ebuf1 = (unsigned*)alloc((size_t)NE * 4);
    unsigned* ebuf2 = (unsigned*)alloc((size_t)NE * 4);

    unsigned short* xa_bf   = (unsigned short*)alloc((size_t)NA_N * DF * 2);
    unsigned short* xb_bf   = (unsigned short*)alloc((size_t)NB_N * DF * 2);
    unsigned short* mean_aa = (unsigned short*)alloc((size_t)NA_N * DF * 2);
    unsigned short* mean_ba = (unsigned short*)alloc((size_t)NA_N * DF * 2);
    unsigned short* mean_ab = (unsigned short*)alloc((size_t)NB_N * DF * 2);
    unsigned short* xa1 = (unsigned short*)alloc((size_t)NA_N * DF * 2);
    unsigned short* xb1 = (unsigned short*)alloc((size_t)NB_N * DF * 2);
    unsigned short* xa2 = mean_ab;  // alias: mean_ab dead once layer-0 dst-b GEMM ran
    unsigned short* Wf[8];
    for (int i = 0; i < 8; i++) Wf[i] = (unsigned short*)alloc((size_t)DF * DF * 2);
    float* pooled = (float*)alloc(NG_N * DF * 4);

    // ---- CSR jobs ----
    CsrJobs CJ;
    CJ.src[0] = ei_aa;      CJ.dst[0] = ei_aa + NE;
    CJ.src[1] = ei_ba;      CJ.dst[1] = ei_ba + NE;
    CJ.src[2] = ei_ab;      CJ.dst[2] = ei_ab + NE;
    CJ.offs[0] = offs_aa;   CJ.ss[0] = ss_aa;   CJ.ebuf[0] = ebuf0;
    CJ.offs[1] = offs_ba;   CJ.ss[1] = ss_ba;   CJ.ebuf[1] = ebuf1;
    CJ.offs[2] = offs_ab;   CJ.ss[2] = ss_ab;   CJ.ebuf[2] = ebuf2;

    WJobs WJ;
    WJ.a[0] = Wn0_aa; WJ.b[0] = nullptr; WJ.d[0] = Wf[0];
    WJ.a[1] = Wn0_ba; WJ.b[1] = nullptr; WJ.d[1] = Wf[1];
    WJ.a[2] = Wr0_aa; WJ.b[2] = Wr0_ba;  WJ.d[2] = Wf[2];
    WJ.a[3] = Wn0_ab; WJ.b[3] = nullptr; WJ.d[3] = Wf[3];
    WJ.a[4] = Wr0_ab; WJ.b[4] = nullptr; WJ.d[4] = Wf[4];
    WJ.a[5] = Wn1_aa; WJ.b[5] = nullptr; WJ.d[5] = Wf[5];
    WJ.a[6] = Wn1_ba; WJ.b[6] = nullptr; WJ.d[6] = Wf[6];
    WJ.a[7] = Wr1_aa; WJ.b[7] = Wr1_ba;  WJ.d[7] = Wf[7];

    // ---- prep + hist (one launch), then scan/bin/sort ----
    hipMemsetAsync(bcnt3, 0, 3 * NBUK * sizeof(int), stream);
    prep_hist_k<<<PREP_BLKS + 3 * BINBLK, 256, 0, stream>>>(
        x_a, x_b, xa_bf, xb_bf, WJ, pooled, CJ, bcnt3);
    bucket_scan3_k<<<3, 512, 0, stream>>>(bcnt3, bbase3, bcur3);
    bucket_bin3_k<<<3 * BINBLK, 256, 0, stream>>>(CJ, bcur3);
    bucket_sort3_k<<<3 * NBUK, 256, 0, stream>>>(CJ, bbase3, NA_N);

    // ---- layer 0: 3 aggregations fused, XCD-partitioned ----
    AggJobs A0;
    A0.xs[0] = xa_bf; A0.offs[0] = offs_aa; A0.ss[0] = ss_aa; A0.mean[0] = mean_aa;
    A0.xs[1] = xb_bf; A0.offs[1] = offs_ba; A0.ss[1] = ss_ba; A0.mean[1] = mean_ba;
    A0.xs[2] = xa_bf; A0.offs[2] = offs_ab; A0.ss[2] = ss_ab; A0.mean[2] = mean_ab;
    aggregate_multi_k<<<AGG0_GRID, 256, 0, stream>>>(A0, 3);

    // ---- layer 0: both GEMMs in one launch ----
    GemmJobs G0;
    G0.A[0][0] = mean_aa; G0.Wf[0][0] = Wf[0];
    G0.A[0][1] = mean_ba; G0.Wf[0][1] = Wf[1];
    G0.A[0][2] = xa_bf;   G0.Wf[0][2] = Wf[2];
    G0.b0[0] = bn0_aa; G0.b1[0] = bn0_ba; G0.outp[0] = xa1; G0.nmats[0] = 3;
    G0.A[1][0] = mean_ab; G0.Wf[1][0] = Wf[3];
    G0.A[1][1] = xb_bf;   G0.Wf[1][1] = Wf[4];
    G0.A[1][2] = nullptr; G0.Wf[1][2] = nullptr;
    G0.b0[1] = bn0_ab; G0.b1[1] = nullptr; G0.outp[1] = xb1; G0.nmats[1] = 2;
    gemm_mfma_multi_k<<<2 * GEMM_BLK, 256, 0, stream>>>(G0);

    // ---- layer 1: 2 aggregations fused, XCD-partitioned ----
    AggJobs A1;
    A1.xs[0] = xa1; A1.offs[0] = offs_aa; A1.ss[0] = ss_aa; A1.mean[0] = mean_aa;
    A1.xs[1] = xb1; A1.offs[1] = offs_ba; A1.ss[1] = ss_ba; A1.mean[1] = mean_ba;
    A1.xs[2] = xa1; A1.offs[2] = offs_aa; A1.ss[2] = ss_aa; A1.mean[2] = mean_aa; // unused
    aggregate_multi_k<<<AGG1_GRID, 256, 0, stream>>>(A1, 2);

    // ---- layer 1 GEMM ----
    GemmJobs G1;
    G1.A[0][0] = mean_aa; G1.Wf[0][0] = Wf[5];
    G1.A[0][1] = mean_ba; G1.Wf[0][1] = Wf[6];
    G1.A[0][2] = xa1;     G1.Wf[0][2] = Wf[7];
    G1.b0[0] = bn1_aa; G1.b1[0] = bn1_ba; G1.outp[0] = xa2; G1.nmats[0] = 3;
    G1.A[1][0] = nullptr; G1.Wf[1][0] = nullptr;
    G1.A[1][1] = nullptr; G1.Wf[1][1] = nullptr;
    G1.A[1][2] = nullptr; G1.Wf[1][2] = nullptr;
    G1.b0[1] = nullptr; G1.b1[1] = nullptr; G1.outp[1] = nullptr; G1.nmats[1] = 0;
    gemm_mfma_multi_k<<<GEMM_BLK, 256, 0, stream>>>(G1);

    // ---- pool + head ----
    pool_partial_k<<<(NA_N + 127) / 128, 256, 0, stream>>>(xa2, batch, pooled);
    out_head_k<<<1, 640, 0, stream>>>(pooled, batch, W_out, b_out, out);
}